// Round 4
// baseline (1811.282 us; speedup 1.0000x reference)
//
#include <hip/hip_runtime.h>
#include <cmath>

#define B_   32
#define S_   128
#define E_   300
#define C_   100
#define EC_  50
#define LC_  50
#define H_   256
#define G4_  1024   // 4*H
#define L_   17
#define DHID_ 400   // E + C
#define NBLKD 8     // lstm blocks per direction
#define SLAB_ 8192  // u32 per (d,t) frag slab: [Nt(2)][Kt(8)][lane(64)][hi m0..3 | lo m0..3]
#define SENT2_ 0x7E007E00u  // fp16-NaN in both halves: legit packed pair never matches

typedef _Float16 half8 __attribute__((ext_vector_type(8)));
typedef float f32x4 __attribute__((ext_vector_type(4)));

// split fp32 -> (hi fp16, lo fp16 scaled by 2048), packed u32 (hi in low16).
__device__ __forceinline__ unsigned pack_split(float v) {
  _Float16 hi = (fabsf(v) >= 6.104e-5f) ? (_Float16)v : (_Float16)0.0f;
  float hif = (float)hi;
  _Float16 lo = (_Float16)((v - hif) * 2048.0f);
  return (unsigned)__builtin_bit_cast(unsigned short, hi)
       | ((unsigned)__builtin_bit_cast(unsigned short, lo) << 16);
}

// ---------------------------------------------------------------- hfrag init: t=0 from h0, t>=1 sentinel
__global__ void k_hinit(const float* __restrict__ h0, unsigned* __restrict__ hfrag) {
  int idx = blockIdx.x * 256 + threadIdx.x;
  const int total = 2 * (S_ + 1) * SLAB_;
  if (idx >= total) return;
  int sd = idx / SLAB_;           // d*(S+1)+t
  int within = idx % SLAB_;
  int t = sd % (S_ + 1), d = sd / (S_ + 1);
  if (t != 0) { hfrag[idx] = SENT2_; return; }
  int m8 = within & 7;            // 0-3 hi words, 4-7 lo words
  int lane = (within >> 3) & 63;
  int q = within >> 9;            // Nt*8+Kt
  int Kt = q & 7, Nt = q >> 3;
  int m = m8 & 3, isLo = m8 >> 2;
  int k0 = Kt * 32 + (lane >> 4) * 8 + 2 * m;
  int b = Nt * 16 + (lane & 15);
  unsigned p0 = pack_split(h0[((size_t)d * B_ + b) * H_ + k0]);
  unsigned p1 = pack_split(h0[((size_t)d * B_ + b) * H_ + k0 + 1]);
  unsigned hiw = (p0 & 0xFFFFu) | (p1 << 16);
  unsigned low = (p0 >> 16) | (p1 & 0xFFFF0000u);
  hfrag[idx] = isLo ? low : hiw;
}

// ---------------------------------------------------------------- char conv1
__global__ void k_conv1(const int* __restrict__ x_char, const float* __restrict__ char_emb,
                        const float* __restrict__ w1, const float* __restrict__ b1,
                        float* __restrict__ out1) {
  int b = blockIdx.x;
  int ot = blockIdx.y;
  __shared__ float ce[EC_ * 52];
  __shared__ float wl[50 * 150];
  __shared__ int ids[LC_];
  int tid = threadIdx.x;
  if (tid < LC_) ids[tid] = x_char[b * LC_ + tid];
  __syncthreads();
  for (int idx = tid; idx < LC_ * EC_; idx += 256) {
    int t = idx / EC_, ec = idx % EC_;
    ce[ec * 52 + t] = char_emb[ids[t] * EC_ + ec];
  }
  int obase = ot * 50;
  for (int idx = tid; idx < 50 * 150; idx += 256)
    wl[idx] = w1[obase * 150 + idx];
  __syncthreads();
  for (int idx = tid; idx < 50 * 48; idx += 256) {
    int o = idx / 48, t = idx % 48;
    float acc = b1[obase + o];
    const float* wr = &wl[o * 150];
    for (int c = 0; c < EC_; ++c) {
      const float* ip = &ce[c * 52 + t];
      acc += wr[c * 3 + 0] * ip[0] + wr[c * 3 + 1] * ip[1] + wr[c * 3 + 2] * ip[2];
    }
    out1[((size_t)b * C_ + obase + o) * 48 + t] = fmaxf(acc, 0.0f);
  }
}

// ---------------------------------------------------------------- char conv2
__global__ void k_conv2(const float* __restrict__ in, const float* __restrict__ w2,
                        const float* __restrict__ b2, float* __restrict__ out2) {
  int b = blockIdx.x, ot = blockIdx.y;
  __shared__ float il[C_ * 48];
  __shared__ float wl[25 * 400];
  int tid = threadIdx.x;
  for (int idx = tid; idx < C_ * 48; idx += 256) il[idx] = in[(size_t)b * C_ * 48 + idx];
  int obase = ot * 25;
  for (int idx = tid; idx < 25 * 400; idx += 256) wl[idx] = w2[obase * 400 + idx];
  __syncthreads();
  for (int idx = tid; idx < 25 * 45; idx += 256) {
    int o = idx / 45, t = idx % 45;
    float acc = b2[obase + o];
    const float* wr = &wl[o * 400];
    for (int c = 0; c < C_; ++c) {
      const float* ip = &il[c * 48 + t];
      acc += wr[c * 4 + 0] * ip[0] + wr[c * 4 + 1] * ip[1] +
             wr[c * 4 + 2] * ip[2] + wr[c * 4 + 3] * ip[3];
    }
    out2[((size_t)b * C_ + obase + o) * 45 + t] = fmaxf(acc, 0.0f);
  }
}

// ---------------------------------------------------------------- char conv3 + maxpool
__global__ void k_conv3(const float* __restrict__ in, const float* __restrict__ w3,
                        const float* __restrict__ b3, float* __restrict__ pooled) {
  int b = blockIdx.x, ot = blockIdx.y;
  __shared__ float il[C_ * 45];
  __shared__ float wl[20 * 500];
  __shared__ float o3[20 * 44];
  int tid = threadIdx.x;
  for (int idx = tid; idx < C_ * 45; idx += 256) il[idx] = in[(size_t)b * C_ * 45 + idx];
  int obase = ot * 20;
  for (int idx = tid; idx < 20 * 500; idx += 256) wl[idx] = w3[obase * 500 + idx];
  __syncthreads();
  for (int idx = tid; idx < 20 * 41; idx += 256) {
    int o = idx / 41, t = idx % 41;
    float acc = b3[obase + o];
    const float* wr = &wl[o * 500];
    for (int c = 0; c < C_; ++c) {
      const float* ip = &il[c * 45 + t];
      acc += wr[c * 5 + 0] * ip[0] + wr[c * 5 + 1] * ip[1] + wr[c * 5 + 2] * ip[2] +
             wr[c * 5 + 3] * ip[3] + wr[c * 5 + 4] * ip[4];
    }
    o3[o * 44 + t] = fmaxf(acc, 0.0f);
  }
  __syncthreads();
  if (tid < 20) {
    float m = o3[tid * 44];
    for (int t = 1; t < 41; ++t) m = fmaxf(m, o3[tid * 44 + t]);
    pooled[b * C_ + obase + tid] = m;
  }
}

// ---------------------------------------------------------------- effective bias -> [d][j][b]
__global__ void k_biaseff(const float* __restrict__ pooled,
                          const float* __restrict__ w_ih_f, const float* __restrict__ b_f,
                          const float* __restrict__ w_ih_b, const float* __restrict__ b_b,
                          float* __restrict__ biaseff) {
  int b = blockIdx.x, d = blockIdx.y;
  const float* wih = d ? w_ih_b : w_ih_f;
  const float* bb = d ? b_b : b_f;
  __shared__ float pl[C_];
  int tid = threadIdx.x;
  if (tid < C_) pl[tid] = pooled[b * C_ + tid];
  __syncthreads();
  for (int j = tid; j < G4_; j += 256) {
    float acc = bb[j];
    const float* wr = &wih[(size_t)j * DHID_ + E_];
    for (int c = 0; c < C_; ++c) acc += pl[c] * wr[c];
    biaseff[((size_t)d * G4_ + j) * B_ + b] = acc;
  }
}

// ---------------------------------------------------------------- input GEMM -> gi[d][t][j][b]
__global__ __launch_bounds__(256) void k_gemm_in(
    const int* __restrict__ x, const float* __restrict__ word_emb,
    const float* __restrict__ w_ih_f, const float* __restrict__ w_ih_b,
    const float* __restrict__ biaseff, float* __restrict__ gi) {
  int jt = blockIdx.x;
  int rt = blockIdx.y;
  int d = blockIdx.z;
  const float* wih = d ? w_ih_b : w_ih_f;
  __shared__ float Al[16][132];
  __shared__ float Bl[16][132];
  __shared__ int wid[128];
  int tid = threadIdx.x;
  int r0 = rt * 128, j0 = jt * 128;
  if (tid < 128) {
    int r = r0 + tid;
    int t = r >> 5, b = r & 31;
    wid[tid] = x[b * S_ + t];
  }
  __syncthreads();
  float acc[8][8];
#pragma unroll
  for (int i = 0; i < 8; ++i)
#pragma unroll
    for (int j = 0; j < 8; ++j) acc[i][j] = 0.f;
  int ty = tid >> 4, tx = tid & 15;

  for (int k0 = 0; k0 < 304; k0 += 16) {
#pragma unroll
    for (int i = 0; i < 2; ++i) {
      int f = tid + i * 256;
      int rl = f >> 2, kc = f & 3;
      const float* src = word_emb + (size_t)wid[rl] * E_;
#pragma unroll
      for (int e = 0; e < 4; ++e) {
        int k = k0 + kc * 4 + e;
        float v = src[k < E_ ? k : (E_ - 1)];
        Al[kc * 4 + e][rl] = (k < E_) ? v : 0.f;
      }
    }
#pragma unroll
    for (int i = 0; i < 2; ++i) {
      int f = tid + i * 256;
      int jl = f >> 2, kc = f & 3;
      const float* src = wih + (size_t)(j0 + jl) * DHID_;
#pragma unroll
      for (int e = 0; e < 4; ++e) {
        int k = k0 + kc * 4 + e;
        float v = src[k];
        Bl[kc * 4 + e][jl] = (k < E_) ? v : 0.f;
      }
    }
    __syncthreads();
#pragma unroll
    for (int kk = 0; kk < 16; ++kk) {
      float4 a0 = *(const float4*)(&Al[kk][ty * 8]);
      float4 a1 = *(const float4*)(&Al[kk][ty * 8 + 4]);
      float4 b0 = *(const float4*)(&Bl[kk][tx * 8]);
      float4 b1 = *(const float4*)(&Bl[kk][tx * 8 + 4]);
      float av[8] = {a0.x, a0.y, a0.z, a0.w, a1.x, a1.y, a1.z, a1.w};
      float bv[8] = {b0.x, b0.y, b0.z, b0.w, b1.x, b1.y, b1.z, b1.w};
#pragma unroll
      for (int i = 0; i < 8; ++i)
#pragma unroll
        for (int j = 0; j < 8; ++j) acc[i][j] = fmaf(av[i], bv[j], acc[i][j]);
    }
    __syncthreads();
  }
  int b0 = (ty & 3) * 8;
  int tt = rt * 4 + (ty >> 2);
#pragma unroll
  for (int jj = 0; jj < 8; ++jj) {
    int j = j0 + tx * 8 + jj;
    const float* be = biaseff + ((size_t)d * G4_ + j) * B_ + b0;
    float4 bl = *(const float4*)(be);
    float4 bh = *(const float4*)(be + 4);
    float4 lo, hi;
    lo.x = acc[0][jj] + bl.x; lo.y = acc[1][jj] + bl.y;
    lo.z = acc[2][jj] + bl.z; lo.w = acc[3][jj] + bl.w;
    hi.x = acc[4][jj] + bh.x; hi.y = acc[5][jj] + bh.y;
    hi.z = acc[6][jj] + bh.z; hi.w = acc[7][jj] + bh.w;
    float* dst = gi + (((size_t)(d * S_ + tt) * G4_) + j) * B_ + b0;
    *(float4*)dst = lo;
    *(float4*)(dst + 4) = hi;
  }
}

// ---------------------------------------------------------------- BiLSTM recurrence via MFMA fp16x2
// grid (NBLKD, 2); block 256 (4 waves), wave = gate. Block iblk owns u in [iblk*32, +32) == K-tile Kt=iblk.
// h exchange DIRECTLY in MFMA B-frag layout: hfrag slab per (d,t):
//   u32[((Nt*8+Kt)*64 + lane)*8 + m], m0..3 = hi j-pair words, m4..7 = lo j-pair words.
// Producers publish with relaxed agent-scope stores; consumers poll u64 loads straight into frag regs.
__global__ __launch_bounds__(256, 1) void k_lstm(
    const float* __restrict__ w_hh_f, const float* __restrict__ w_hh_b,
    const float* __restrict__ c0, const float* __restrict__ gi,
    float* __restrict__ hbuf, unsigned* __restrict__ hfrag) {
  const int iblk = blockIdx.x;     // 0..7
  const int d = blockIdx.y;
  const float* whh = d ? w_hh_b : w_hh_f;
  const int tid = threadIdx.x;
  const int w = tid >> 6;          // wave index = gate (i,f,g,o)
  const int l = tid & 63;
  const int lx = l & 15, lq = l >> 4;
  const int u0 = iblk * 32;

  __shared__ float gl[4 * 32 * 33];     // [gate][u][b]

  // ---- persistent W fragments: A[m=lane&15][k=(lane>>4)*8+j]
  half8 whi[2][8], wlo[2][8];
#pragma unroll
  for (int Mt = 0; Mt < 2; ++Mt) {
#pragma unroll
    for (int Kt = 0; Kt < 8; ++Kt) {
      int row = w * H_ + u0 + Mt * 16 + lx;
      int kk0 = Kt * 32 + lq * 8;
      const float* src = whh + (size_t)row * H_ + kk0;
      float4 f0 = *(const float4*)src;
      float4 f1 = *(const float4*)(src + 4);
      float wv[8] = {f0.x, f0.y, f0.z, f0.w, f1.x, f1.y, f1.z, f1.w};
      union { unsigned short s[8]; half8 h; } HI, LO;
#pragma unroll
      for (int j = 0; j < 8; ++j) {
        float v = wv[j];
        _Float16 hi = (fabsf(v) >= 6.104e-5f) ? (_Float16)v : (_Float16)0.0f;
        float hif = (float)hi;
        _Float16 lo = (_Float16)((v - hif) * 2048.0f);
        HI.s[j] = __builtin_bit_cast(unsigned short, hi);
        LO.s[j] = __builtin_bit_cast(unsigned short, lo);
      }
      whi[Mt][Kt] = HI.h;
      wlo[Mt][Kt] = LO.h;
    }
  }

  // cell state: thread (bc = tid&31, cw = tid>>5 in 0..7) owns u = cu*8+cw
  const int bc = tid & 31, cw = tid >> 5;
  float creg[4];
#pragma unroll
  for (int cu = 0; cu < 4; ++cu)
    creg[cu] = c0[((size_t)d * B_ + bc) * H_ + u0 + cu * 8 + cw];

  // publish constants for this thread
  const int pNt = bc >> 4;
  const int pm = cw >> 1;
  const bool phi = (cw & 1) == 0;
  const float inv2048 = 1.0f / 2048.0f;

  for (int t = 0; t < S_; ++t) {
    int torig = d ? (S_ - 1 - t) : t;

    // gate-input frags (independent of h): init acc_hi with gi (C-operand trick)
    f32x4 acch[2][2], accl[2][2];
    {
      const float* gbase = gi + ((size_t)(d * S_ + torig) * G4_) * B_;
#pragma unroll
      for (int Mt = 0; Mt < 2; ++Mt)
#pragma unroll
        for (int Nt = 0; Nt < 2; ++Nt) {
          f32x4 v;
#pragma unroll
          for (int r = 0; r < 4; ++r) {
            int j = w * H_ + u0 + Mt * 16 + lq * 4 + r;
            v[r] = gbase[(size_t)j * B_ + Nt * 16 + lx];
          }
          acch[Mt][Nt] = v;
          f32x4 z = {0.f, 0.f, 0.f, 0.f};
          accl[Mt][Nt] = z;
        }
    }

    // poll h(t) frag slab straight into registers (u64 relaxed agent-scope loads)
    const unsigned long long* hp =
        (const unsigned long long*)(hfrag + (size_t)(d * (S_ + 1) + t) * SLAB_);
    unsigned long long vh[16][2], vl[16][2];
#pragma unroll
    for (int q = 0; q < 16; ++q) {
      size_t base = ((size_t)q * 64 + l) * 4;   // u64 units
      vh[q][0] = __hip_atomic_load(&hp[base + 0], __ATOMIC_RELAXED, __HIP_MEMORY_SCOPE_AGENT);
      vh[q][1] = __hip_atomic_load(&hp[base + 1], __ATOMIC_RELAXED, __HIP_MEMORY_SCOPE_AGENT);
      vl[q][0] = __hip_atomic_load(&hp[base + 2], __ATOMIC_RELAXED, __HIP_MEMORY_SCOPE_AGENT);
      vl[q][1] = __hip_atomic_load(&hp[base + 3], __ATOMIC_RELAXED, __HIP_MEMORY_SCOPE_AGENT);
    }
    for (;;) {
      bool pending = false;
#pragma unroll
      for (int q = 0; q < 16; ++q)
#pragma unroll
        for (int i = 0; i < 2; ++i) {
          pending |= ((unsigned)vh[q][i] == SENT2_) | ((unsigned)(vh[q][i] >> 32) == SENT2_);
          pending |= ((unsigned)vl[q][i] == SENT2_) | ((unsigned)(vl[q][i] >> 32) == SENT2_);
        }
      if (!pending) break;
#pragma unroll
      for (int q = 0; q < 16; ++q) {
        size_t base = ((size_t)q * 64 + l) * 4;
#pragma unroll
        for (int i = 0; i < 2; ++i) {
          if (((unsigned)vh[q][i] == SENT2_) | ((unsigned)(vh[q][i] >> 32) == SENT2_))
            vh[q][i] = __hip_atomic_load(&hp[base + i], __ATOMIC_RELAXED, __HIP_MEMORY_SCOPE_AGENT);
          if (((unsigned)vl[q][i] == SENT2_) | ((unsigned)(vl[q][i] >> 32) == SENT2_))
            vl[q][i] = __hip_atomic_load(&hp[base + 2 + i], __ATOMIC_RELAXED, __HIP_MEMORY_SCOPE_AGENT);
        }
      }
    }

    // MFMA: frag regs are ready as-is (no repack)
#pragma unroll
    for (int Kt = 0; Kt < 8; ++Kt) {
      half8 Bhi[2], Blo[2];
#pragma unroll
      for (int Nt = 0; Nt < 2; ++Nt) {
        int q = Nt * 8 + Kt;
        union { unsigned long long q2[2]; half8 h; } U, V;
        U.q2[0] = vh[q][0]; U.q2[1] = vh[q][1];
        V.q2[0] = vl[q][0]; V.q2[1] = vl[q][1];
        Bhi[Nt] = U.h;
        Blo[Nt] = V.h;
      }
#pragma unroll
      for (int Mt = 0; Mt < 2; ++Mt)
#pragma unroll
        for (int Nt = 0; Nt < 2; ++Nt) {
          acch[Mt][Nt] = __builtin_amdgcn_mfma_f32_16x16x32_f16(
              whi[Mt][Kt], Bhi[Nt], acch[Mt][Nt], 0, 0, 0);
          accl[Mt][Nt] = __builtin_amdgcn_mfma_f32_16x16x32_f16(
              whi[Mt][Kt], Blo[Nt], accl[Mt][Nt], 0, 0, 0);
          accl[Mt][Nt] = __builtin_amdgcn_mfma_f32_16x16x32_f16(
              wlo[Mt][Kt], Bhi[Nt], accl[Mt][Nt], 0, 0, 0);
        }
    }

    // gates -> gl ; C/D layout: col=lane&15, row=(lane>>4)*4+reg
#pragma unroll
    for (int Mt = 0; Mt < 2; ++Mt)
#pragma unroll
      for (int Nt = 0; Nt < 2; ++Nt)
#pragma unroll
        for (int r = 0; r < 4; ++r) {
          int ul = Mt * 16 + lq * 4 + r;
          gl[(w * 32 + ul) * 33 + Nt * 16 + lx] =
              acch[Mt][Nt][r] + accl[Mt][Nt][r] * inv2048;
        }
    __syncthreads();

    // cell update + publish in frag layout
    unsigned* slab = hfrag + (size_t)(d * (S_ + 1) + t + 1) * SLAB_;
    float* hb = hbuf + (size_t)(d * (S_ + 1) + t + 1) * (H_ * B_) + u0 * B_;
#pragma unroll
    for (int cu = 0; cu < 4; ++cu) {
      int u = cu * 8 + cw;
      float g_i = gl[(0 * 32 + u) * 33 + bc];
      float g_f = gl[(1 * 32 + u) * 33 + bc];
      float g_g = gl[(2 * 32 + u) * 33 + bc];
      float g_o = gl[(3 * 32 + u) * 33 + bc];
      float si = 1.f / (1.f + expf(-g_i));
      float sf = 1.f / (1.f + expf(-g_f));
      float so = 1.f / (1.f + expf(-g_o));
      float tg = tanhf(g_g);
      float cn = sf * creg[cu] + si * tg;
      float hn = so * tanhf(cn);
      creg[cu] = cn;
      hb[cu * 256 + tid] = hn;  // hbuf fp32 [k][b], fully coalesced; wait—only if cw*32+bc==tid: yes
      unsigned me = pack_split(hn);
      unsigned pa = (unsigned)__shfl_xor((int)me, 32, 64);  // partner cw^1 (same bc,cu)
      unsigned je = (cw & 1) ? pa : me;
      unsigned jo = (cw & 1) ? me : pa;
      unsigned hiw = (je & 0xFFFFu) | (jo << 16);
      unsigned low = (je >> 16) | (jo & 0xFFFF0000u);
      int lane = (cu << 4) | (bc & 15);
      size_t base = ((size_t)(pNt * 8 + iblk) * 64 + lane) * 8;
      if (phi)
        __hip_atomic_store(&slab[base + pm], hiw, __ATOMIC_RELAXED, __HIP_MEMORY_SCOPE_AGENT);
      else
        __hip_atomic_store(&slab[base + 4 + pm], low, __ATOMIC_RELAXED, __HIP_MEMORY_SCOPE_AGENT);
    }
    __syncthreads();   // protect gl (WAR) before next iteration's writes
  }
}

// ---------------------------------------------------------------- FC -> emissions em[b][s][l]
__global__ void k_fc(const float* __restrict__ hbuf, const float* __restrict__ fc_w,
                     const float* __restrict__ fc_b, float* __restrict__ em) {
  int idx = blockIdx.x * 256 + threadIdx.x;
  if (idx >= B_ * S_ * L_) return;
  int l = idx % L_;
  int bs = idx / L_;
  int s = bs % S_;
  int b = bs / S_;
  const float* hf = hbuf + ((size_t)(s + 1)) * (H_ * B_);
  const float* hb = hbuf + ((size_t)(S_ + 1) + (S_ - s)) * ((size_t)H_ * B_);
  const float* w = fc_w + (size_t)l * (2 * H_);
  float acc = fc_b[l];
  for (int k = 0; k < H_; ++k) acc = fmaf(hf[k * B_ + b], w[k], acc);
  for (int k = 0; k < H_; ++k) acc = fmaf(hb[k * B_ + b], w[H_ + k], acc);
  em[(size_t)idx] = acc;
}

// ---------------------------------------------------------------- softmax over SEQ dim (faithful)
__global__ void k_softmax(float* __restrict__ em) {
  int b = blockIdx.x;
  __shared__ float e[S_ * L_];
  int tid = threadIdx.x;
  for (int i = tid; i < S_ * L_; i += 256) e[i] = em[(size_t)b * S_ * L_ + i];
  __syncthreads();
  if (tid < L_) {
    int l = tid;
    float m = -INFINITY;
    for (int s = 0; s < S_; ++s) m = fmaxf(m, e[s * L_ + l]);
    float sum = 0.f;
    for (int s = 0; s < S_; ++s) {
      float ex = expf(e[s * L_ + l] - m);
      e[s * L_ + l] = ex;
      sum += ex;
    }
    for (int s = 0; s < S_; ++s) e[s * L_ + l] = e[s * L_ + l] / sum;
  }
  __syncthreads();
  for (int i = tid; i < S_ * L_; i += 256) em[(size_t)b * S_ * L_ + i] = e[i];
}

// ---------------------------------------------------------------- Viterbi (one block per batch)
__global__ void k_viterbi(const float* __restrict__ em, const int* __restrict__ x,
                          const float* __restrict__ start_t, const float* __restrict__ trans,
                          const float* __restrict__ end_t, int* __restrict__ hist,
                          int* __restrict__ out) {
  int b = blockIdx.x;
  __shared__ float tr[L_ * L_];
  __shared__ float sc[2][L_];
  int tid = threadIdx.x;
  for (int i = tid; i < L_ * L_; i += 64) tr[i] = trans[i];
  if (tid < L_) sc[0][tid] = start_t[tid] + em[((size_t)b * S_ + 0) * L_ + tid];
  __syncthreads();
  int cbuf = 0;
  for (int t = 1; t < S_; ++t) {
    if (tid < L_) {
      int j = tid;
      float e = em[((size_t)b * S_ + t) * L_ + j];
      float best = -INFINITY;
      int arg = 0;
      for (int i = 0; i < L_; ++i) {
        float v = (sc[cbuf][i] + tr[i * L_ + j]) + e;
        if (v > best) { best = v; arg = i; }  // strict >: first occurrence like np.argmax
      }
      int maskt = (x[b * S_ + t] != 0);
      sc[cbuf ^ 1][j] = maskt ? best : sc[cbuf][j];
      hist[((size_t)(t - 1) * B_ + b) * L_ + j] = arg;
    }
    __syncthreads();
    cbuf ^= 1;
  }
  __syncthreads();
  if (tid == 0) {
    float best = -INFINITY;
    int last = 0;
    for (int j = 0; j < L_; ++j) {
      float v = sc[cbuf][j] + end_t[j];
      if (v > best) { best = v; last = j; }
    }
    int cur = last;
    out[b * S_ + S_ - 1] = cur;
    for (int p = S_ - 2; p >= 0; --p) {
      if (x[b * S_ + p + 1] != 0) cur = hist[((size_t)p * B_ + b) * L_ + cur];
      out[b * S_ + p] = cur;
    }
  }
}

// ---------------------------------------------------------------- launch
extern "C" void kernel_launch(void* const* d_in, const int* in_sizes, int n_in,
                              void* d_out, int out_size, void* d_ws, size_t ws_size,
                              hipStream_t stream) {
  const int* x        = (const int*)d_in[0];
  const int* x_char   = (const int*)d_in[1];
  const float* word_emb = (const float*)d_in[2];
  const float* char_emb = (const float*)d_in[3];
  const float* conv1_w = (const float*)d_in[4];
  const float* conv1_b = (const float*)d_in[5];
  const float* conv2_w = (const float*)d_in[6];
  const float* conv2_b = (const float*)d_in[7];
  const float* conv3_w = (const float*)d_in[8];
  const float* conv3_b = (const float*)d_in[9];
  const float* w_ih_f = (const float*)d_in[10];
  const float* w_hh_f = (const float*)d_in[11];
  const float* b_f    = (const float*)d_in[12];
  const float* w_ih_b = (const float*)d_in[13];
  const float* w_hh_b = (const float*)d_in[14];
  const float* b_b    = (const float*)d_in[15];
  const float* h0     = (const float*)d_in[16];
  const float* c0     = (const float*)d_in[17];
  const float* fc_w   = (const float*)d_in[18];
  const float* fc_b   = (const float*)d_in[19];
  const float* start_t = (const float*)d_in[20];
  const float* trans  = (const float*)d_in[21];
  const float* end_t  = (const float*)d_in[22];
  int* out = (int*)d_out;

  char* ws = (char*)d_ws;
  auto alloc = [&](size_t bytes) -> char* {
    char* p = ws;
    ws += (bytes + 1023) & ~(size_t)1023;
    return p;
  };
  float* pooled  = (float*)alloc(sizeof(float) * B_ * C_);
  float* biaseff = (float*)alloc(sizeof(float) * 2 * G4_ * B_);
  float* gi      = (float*)alloc(sizeof(float) * 2 * S_ * G4_ * B_);          // 33.5 MB
  float* hbuf    = (float*)alloc(sizeof(float) * 2 * (S_ + 1) * H_ * B_);     // 8.45 MB
  unsigned* hfrag = (unsigned*)alloc(sizeof(unsigned) * 2 * (S_ + 1) * SLAB_); // 8.45 MB
  float* out1    = (float*)alloc(sizeof(float) * B_ * C_ * 48);
  float* out2    = (float*)alloc(sizeof(float) * B_ * C_ * 45);
  float* em      = (float*)alloc(sizeof(float) * B_ * S_ * L_);
  int* hist      = (int*)alloc(sizeof(int) * (S_ - 1) * B_ * L_);

  const int hinit_total = 2 * (S_ + 1) * SLAB_;
  k_hinit<<<(hinit_total + 255) / 256, 256, 0, stream>>>(h0, hfrag);
  k_conv1<<<dim3(32, 2), 256, 0, stream>>>(x_char, char_emb, conv1_w, conv1_b, out1);
  k_conv2<<<dim3(32, 4), 256, 0, stream>>>(out1, conv2_w, conv2_b, out2);
  k_conv3<<<dim3(32, 5), 256, 0, stream>>>(out2, conv3_w, conv3_b, pooled);
  k_biaseff<<<dim3(32, 2), 256, 0, stream>>>(pooled, w_ih_f, b_f, w_ih_b, b_b, biaseff);
  k_gemm_in<<<dim3(8, 32, 2), 256, 0, stream>>>(x, word_emb, w_ih_f, w_ih_b, biaseff, gi);
  k_lstm<<<dim3(NBLKD, 2), 256, 0, stream>>>(w_hh_f, w_hh_b, c0, gi, hbuf, hfrag);
  k_fc<<<(B_ * S_ * L_ + 255) / 256, 256, 0, stream>>>(hbuf, fc_w, fc_b, em);
  k_softmax<<<32, 256, 0, stream>>>(em);
  k_viterbi<<<32, 64, 0, stream>>>(em, x, start_t, trans, end_t, hist, out);
}

// Round 5
// 1485.057 us; speedup vs baseline: 1.2197x; 1.2197x over previous
//
#include <hip/hip_runtime.h>
#include <cmath>

#define B_   32
#define S_   128
#define E_   300
#define C_   100
#define EC_  50
#define LC_  50
#define H_   256
#define G4_  1024   // 4*H
#define L_   17
#define DHID_ 400   // E + C
#define NBLKD 8     // lstm blocks per direction
#define SLAB_ 8192  // u32 per (d,t) frag slab: [Nt(2)][Kt(8)][lane(64)][hi m0..3 | lo m0..3]
#define SENT2_ 0x7E007E00u  // fp16-NaN in both halves: legit packed pair never matches

typedef _Float16 half8 __attribute__((ext_vector_type(8)));
typedef float f32x4 __attribute__((ext_vector_type(4)));

// split fp32 -> (hi fp16, lo fp16 scaled by 2048), packed u32 (hi in low16).
__device__ __forceinline__ unsigned pack_split(float v) {
  _Float16 hi = (fabsf(v) >= 6.104e-5f) ? (_Float16)v : (_Float16)0.0f;
  float hif = (float)hi;
  _Float16 lo = (_Float16)((v - hif) * 2048.0f);
  return (unsigned)__builtin_bit_cast(unsigned short, hi)
       | ((unsigned)__builtin_bit_cast(unsigned short, lo) << 16);
}

// ---------------------------------------------------------------- hfrag init: t=0 from h0, t>=1 sentinel
__global__ void k_hinit(const float* __restrict__ h0, unsigned* __restrict__ hfrag) {
  int idx = blockIdx.x * 256 + threadIdx.x;
  const int total = 2 * (S_ + 1) * SLAB_;
  if (idx >= total) return;
  int sd = idx / SLAB_;           // d*(S+1)+t
  int within = idx % SLAB_;
  int t = sd % (S_ + 1), d = sd / (S_ + 1);
  if (t != 0) { hfrag[idx] = SENT2_; return; }
  int m8 = within & 7;            // 0-3 hi words, 4-7 lo words
  int lane = (within >> 3) & 63;
  int q = within >> 9;            // Nt*8+Kt
  int Kt = q & 7, Nt = q >> 3;
  int m = m8 & 3, isLo = m8 >> 2;
  int k0 = Kt * 32 + (lane >> 4) * 8 + 2 * m;
  int b = Nt * 16 + (lane & 15);
  unsigned p0 = pack_split(h0[((size_t)d * B_ + b) * H_ + k0]);
  unsigned p1 = pack_split(h0[((size_t)d * B_ + b) * H_ + k0 + 1]);
  unsigned hiw = (p0 & 0xFFFFu) | (p1 << 16);
  unsigned low = (p0 >> 16) | (p1 & 0xFFFF0000u);
  hfrag[idx] = isLo ? low : hiw;
}

// ---------------------------------------------------------------- char conv1
__global__ void k_conv1(const int* __restrict__ x_char, const float* __restrict__ char_emb,
                        const float* __restrict__ w1, const float* __restrict__ b1,
                        float* __restrict__ out1) {
  int b = blockIdx.x;
  int ot = blockIdx.y;
  __shared__ float ce[EC_ * 52];
  __shared__ float wl[50 * 150];
  __shared__ int ids[LC_];
  int tid = threadIdx.x;
  if (tid < LC_) ids[tid] = x_char[b * LC_ + tid];
  __syncthreads();
  for (int idx = tid; idx < LC_ * EC_; idx += 256) {
    int t = idx / EC_, ec = idx % EC_;
    ce[ec * 52 + t] = char_emb[ids[t] * EC_ + ec];
  }
  int obase = ot * 50;
  for (int idx = tid; idx < 50 * 150; idx += 256)
    wl[idx] = w1[obase * 150 + idx];
  __syncthreads();
  for (int idx = tid; idx < 50 * 48; idx += 256) {
    int o = idx / 48, t = idx % 48;
    float acc = b1[obase + o];
    const float* wr = &wl[o * 150];
    for (int c = 0; c < EC_; ++c) {
      const float* ip = &ce[c * 52 + t];
      acc += wr[c * 3 + 0] * ip[0] + wr[c * 3 + 1] * ip[1] + wr[c * 3 + 2] * ip[2];
    }
    out1[((size_t)b * C_ + obase + o) * 48 + t] = fmaxf(acc, 0.0f);
  }
}

// ---------------------------------------------------------------- char conv2
__global__ void k_conv2(const float* __restrict__ in, const float* __restrict__ w2,
                        const float* __restrict__ b2, float* __restrict__ out2) {
  int b = blockIdx.x, ot = blockIdx.y;
  __shared__ float il[C_ * 48];
  __shared__ float wl[25 * 400];
  int tid = threadIdx.x;
  for (int idx = tid; idx < C_ * 48; idx += 256) il[idx] = in[(size_t)b * C_ * 48 + idx];
  int obase = ot * 25;
  for (int idx = tid; idx < 25 * 400; idx += 256) wl[idx] = w2[obase * 400 + idx];
  __syncthreads();
  for (int idx = tid; idx < 25 * 45; idx += 256) {
    int o = idx / 45, t = idx % 45;
    float acc = b2[obase + o];
    const float* wr = &wl[o * 400];
    for (int c = 0; c < C_; ++c) {
      const float* ip = &il[c * 48 + t];
      acc += wr[c * 4 + 0] * ip[0] + wr[c * 4 + 1] * ip[1] +
             wr[c * 4 + 2] * ip[2] + wr[c * 4 + 3] * ip[3];
    }
    out2[((size_t)b * C_ + obase + o) * 45 + t] = fmaxf(acc, 0.0f);
  }
}

// ---------------------------------------------------------------- char conv3 + maxpool
__global__ void k_conv3(const float* __restrict__ in, const float* __restrict__ w3,
                        const float* __restrict__ b3, float* __restrict__ pooled) {
  int b = blockIdx.x, ot = blockIdx.y;
  __shared__ float il[C_ * 45];
  __shared__ float wl[20 * 500];
  __shared__ float o3[20 * 44];
  int tid = threadIdx.x;
  for (int idx = tid; idx < C_ * 45; idx += 256) il[idx] = in[(size_t)b * C_ * 45 + idx];
  int obase = ot * 20;
  for (int idx = tid; idx < 20 * 500; idx += 256) wl[idx] = w3[obase * 500 + idx];
  __syncthreads();
  for (int idx = tid; idx < 20 * 41; idx += 256) {
    int o = idx / 41, t = idx % 41;
    float acc = b3[obase + o];
    const float* wr = &wl[o * 500];
    for (int c = 0; c < C_; ++c) {
      const float* ip = &il[c * 45 + t];
      acc += wr[c * 5 + 0] * ip[0] + wr[c * 5 + 1] * ip[1] + wr[c * 5 + 2] * ip[2] +
             wr[c * 5 + 3] * ip[3] + wr[c * 5 + 4] * ip[4];
    }
    o3[o * 44 + t] = fmaxf(acc, 0.0f);
  }
  __syncthreads();
  if (tid < 20) {
    float m = o3[tid * 44];
    for (int t = 1; t < 41; ++t) m = fmaxf(m, o3[tid * 44 + t]);
    pooled[b * C_ + obase + tid] = m;
  }
}

// ---------------------------------------------------------------- effective bias -> [d][j][b]
__global__ void k_biaseff(const float* __restrict__ pooled,
                          const float* __restrict__ w_ih_f, const float* __restrict__ b_f,
                          const float* __restrict__ w_ih_b, const float* __restrict__ b_b,
                          float* __restrict__ biaseff) {
  int b = blockIdx.x, d = blockIdx.y;
  const float* wih = d ? w_ih_b : w_ih_f;
  const float* bb = d ? b_b : b_f;
  __shared__ float pl[C_];
  int tid = threadIdx.x;
  if (tid < C_) pl[tid] = pooled[b * C_ + tid];
  __syncthreads();
  for (int j = tid; j < G4_; j += 256) {
    float acc = bb[j];
    const float* wr = &wih[(size_t)j * DHID_ + E_];
    for (int c = 0; c < C_; ++c) acc += pl[c] * wr[c];
    biaseff[((size_t)d * G4_ + j) * B_ + b] = acc;
  }
}

// ---------------------------------------------------------------- input GEMM -> gi[d][t][j][b]
__global__ __launch_bounds__(256) void k_gemm_in(
    const int* __restrict__ x, const float* __restrict__ word_emb,
    const float* __restrict__ w_ih_f, const float* __restrict__ w_ih_b,
    const float* __restrict__ biaseff, float* __restrict__ gi) {
  int jt = blockIdx.x;
  int rt = blockIdx.y;
  int d = blockIdx.z;
  const float* wih = d ? w_ih_b : w_ih_f;
  __shared__ float Al[16][132];
  __shared__ float Bl[16][132];
  __shared__ int wid[128];
  int tid = threadIdx.x;
  int r0 = rt * 128, j0 = jt * 128;
  if (tid < 128) {
    int r = r0 + tid;
    int t = r >> 5, b = r & 31;
    wid[tid] = x[b * S_ + t];
  }
  __syncthreads();
  float acc[8][8];
#pragma unroll
  for (int i = 0; i < 8; ++i)
#pragma unroll
    for (int j = 0; j < 8; ++j) acc[i][j] = 0.f;
  int ty = tid >> 4, tx = tid & 15;

  for (int k0 = 0; k0 < 304; k0 += 16) {
#pragma unroll
    for (int i = 0; i < 2; ++i) {
      int f = tid + i * 256;
      int rl = f >> 2, kc = f & 3;
      const float* src = word_emb + (size_t)wid[rl] * E_;
#pragma unroll
      for (int e = 0; e < 4; ++e) {
        int k = k0 + kc * 4 + e;
        float v = src[k < E_ ? k : (E_ - 1)];
        Al[kc * 4 + e][rl] = (k < E_) ? v : 0.f;
      }
    }
#pragma unroll
    for (int i = 0; i < 2; ++i) {
      int f = tid + i * 256;
      int jl = f >> 2, kc = f & 3;
      const float* src = wih + (size_t)(j0 + jl) * DHID_;
#pragma unroll
      for (int e = 0; e < 4; ++e) {
        int k = k0 + kc * 4 + e;
        float v = src[k];
        Bl[kc * 4 + e][jl] = (k < E_) ? v : 0.f;
      }
    }
    __syncthreads();
#pragma unroll
    for (int kk = 0; kk < 16; ++kk) {
      float4 a0 = *(const float4*)(&Al[kk][ty * 8]);
      float4 a1 = *(const float4*)(&Al[kk][ty * 8 + 4]);
      float4 b0 = *(const float4*)(&Bl[kk][tx * 8]);
      float4 b1 = *(const float4*)(&Bl[kk][tx * 8 + 4]);
      float av[8] = {a0.x, a0.y, a0.z, a0.w, a1.x, a1.y, a1.z, a1.w};
      float bv[8] = {b0.x, b0.y, b0.z, b0.w, b1.x, b1.y, b1.z, b1.w};
#pragma unroll
      for (int i = 0; i < 8; ++i)
#pragma unroll
        for (int j = 0; j < 8; ++j) acc[i][j] = fmaf(av[i], bv[j], acc[i][j]);
    }
    __syncthreads();
  }
  int b0 = (ty & 3) * 8;
  int tt = rt * 4 + (ty >> 2);
#pragma unroll
  for (int jj = 0; jj < 8; ++jj) {
    int j = j0 + tx * 8 + jj;
    const float* be = biaseff + ((size_t)d * G4_ + j) * B_ + b0;
    float4 bl = *(const float4*)(be);
    float4 bh = *(const float4*)(be + 4);
    float4 lo, hi;
    lo.x = acc[0][jj] + bl.x; lo.y = acc[1][jj] + bl.y;
    lo.z = acc[2][jj] + bl.z; lo.w = acc[3][jj] + bl.w;
    hi.x = acc[4][jj] + bh.x; hi.y = acc[5][jj] + bh.y;
    hi.z = acc[6][jj] + bh.z; hi.w = acc[7][jj] + bh.w;
    float* dst = gi + (((size_t)(d * S_ + tt) * G4_) + j) * B_ + b0;
    *(float4*)dst = lo;
    *(float4*)(dst + 4) = hi;
  }
}

// ---------------------------------------------------------------- BiLSTM recurrence via MFMA fp16x2
// grid (NBLKD, 2); block 256 (4 waves), wave = gate. Block iblk owns u in [iblk*32,+32) == K-tile Kt=iblk.
// h exchange in MFMA B-frag layout (hfrag slab per (d,t)). R5 mechanics:
//  - consume: per-Kt chunks (8 u64 live) with one-chunk prefetch, straight into MFMA (no LDS, low VGPR)
//  - publish: stage into 4KB LDS in slab order, then 2 fully-coalesced u64 agent-atomic stores/thread
__global__ __launch_bounds__(256, 1) void k_lstm(
    const float* __restrict__ w_hh_f, const float* __restrict__ w_hh_b,
    const float* __restrict__ c0, const float* __restrict__ gi,
    float* __restrict__ hbuf, unsigned* __restrict__ hfrag) {
  const int iblk = blockIdx.x;     // 0..7
  const int d = blockIdx.y;
  const float* whh = d ? w_hh_b : w_hh_f;
  const int tid = threadIdx.x;
  const int w = tid >> 6;          // wave index = gate (i,f,g,o)
  const int l = tid & 63;
  const int lx = l & 15, lq = l >> 4;
  const int u0 = iblk * 32;

  __shared__ float gl[4 * 32 * 33];               // [gate][u][b]
  __shared__ __align__(16) unsigned ps[1024];     // publish staging, slab order (4KB)

  // ---- persistent W fragments: A[m=lane&15][k=(lane>>4)*8+j]
  half8 whi[2][8], wlo[2][8];
#pragma unroll
  for (int Mt = 0; Mt < 2; ++Mt) {
#pragma unroll
    for (int Kt = 0; Kt < 8; ++Kt) {
      int row = w * H_ + u0 + Mt * 16 + lx;
      int kk0 = Kt * 32 + lq * 8;
      const float* src = whh + (size_t)row * H_ + kk0;
      float4 f0 = *(const float4*)src;
      float4 f1 = *(const float4*)(src + 4);
      float wv[8] = {f0.x, f0.y, f0.z, f0.w, f1.x, f1.y, f1.z, f1.w};
      union { unsigned short s[8]; half8 h; } HI, LO;
#pragma unroll
      for (int j = 0; j < 8; ++j) {
        float v = wv[j];
        _Float16 hi = (fabsf(v) >= 6.104e-5f) ? (_Float16)v : (_Float16)0.0f;
        float hif = (float)hi;
        _Float16 lo = (_Float16)((v - hif) * 2048.0f);
        HI.s[j] = __builtin_bit_cast(unsigned short, hi);
        LO.s[j] = __builtin_bit_cast(unsigned short, lo);
      }
      whi[Mt][Kt] = HI.h;
      wlo[Mt][Kt] = LO.h;
    }
  }

  // cell state: thread (bc = tid&31, cw = tid>>5 in 0..7) owns u = cu*8+cw
  const int bc = tid & 31, cw = tid >> 5;
  float creg[4];
#pragma unroll
  for (int cu = 0; cu < 4; ++cu)
    creg[cu] = c0[((size_t)d * B_ + bc) * H_ + u0 + cu * 8 + cw];

  const int pNt = bc >> 4;
  const int pm = cw >> 1;
  const bool phi = (cw & 1) == 0;
  const float inv2048 = 1.0f / 2048.0f;

  for (int t = 0; t < S_; ++t) {
    int torig = d ? (S_ - 1 - t) : t;

    // gate-input frags (independent of h): init acc_hi with gi (C-operand trick)
    f32x4 acch[2][2], accl[2][2];
    {
      const float* gbase = gi + ((size_t)(d * S_ + torig) * G4_) * B_;
#pragma unroll
      for (int Mt = 0; Mt < 2; ++Mt)
#pragma unroll
        for (int Nt = 0; Nt < 2; ++Nt) {
          f32x4 v;
#pragma unroll
          for (int r = 0; r < 4; ++r) {
            int j = w * H_ + u0 + Mt * 16 + lq * 4 + r;
            v[r] = gbase[(size_t)j * B_ + Nt * 16 + lx];
          }
          acch[Mt][Nt] = v;
          f32x4 z = {0.f, 0.f, 0.f, 0.f};
          accl[Mt][Nt] = z;
        }
    }

    // chunked poll + MFMA over Kt, one-chunk prefetch ahead
    const unsigned long long* hp =
        (const unsigned long long*)(hfrag + (size_t)(d * (S_ + 1) + t) * SLAB_);
    unsigned long long cur[8], nxt[8];
#pragma unroll
    for (int i = 0; i < 2; ++i) {
      size_t base = ((size_t)(i * 8 + 0) * 64 + l) * 4;
#pragma unroll
      for (int j = 0; j < 4; ++j)
        cur[i * 4 + j] = __hip_atomic_load(&hp[base + j], __ATOMIC_RELAXED,
                                           __HIP_MEMORY_SCOPE_AGENT);
    }
#pragma unroll
    for (int Kt = 0; Kt < 8; ++Kt) {
      if (Kt < 7) {
#pragma unroll
        for (int i = 0; i < 2; ++i) {
          size_t base = ((size_t)(i * 8 + Kt + 1) * 64 + l) * 4;
#pragma unroll
          for (int j = 0; j < 4; ++j)
            nxt[i * 4 + j] = __hip_atomic_load(&hp[base + j], __ATOMIC_RELAXED,
                                               __HIP_MEMORY_SCOPE_AGENT);
        }
      }
      // retry current chunk until sentinel-free
      for (;;) {
        bool pending = false;
#pragma unroll
        for (int e = 0; e < 8; ++e)
          pending |= ((unsigned)cur[e] == SENT2_) | ((unsigned)(cur[e] >> 32) == SENT2_);
        if (!pending) break;
#pragma unroll
        for (int e = 0; e < 8; ++e) {
          if (((unsigned)cur[e] == SENT2_) | ((unsigned)(cur[e] >> 32) == SENT2_)) {
            size_t base = ((size_t)((e >> 2) * 8 + Kt) * 64 + l) * 4 + (e & 3);
            cur[e] = __hip_atomic_load(&hp[base], __ATOMIC_RELAXED,
                                       __HIP_MEMORY_SCOPE_AGENT);
          }
        }
      }
      // unpack (register-only) and MFMA
      half8 Bhi[2], Blo[2];
#pragma unroll
      for (int Nt = 0; Nt < 2; ++Nt) {
        union { unsigned long long q2[2]; half8 h; } U, V;
        U.q2[0] = cur[Nt * 4 + 0]; U.q2[1] = cur[Nt * 4 + 1];
        V.q2[0] = cur[Nt * 4 + 2]; V.q2[1] = cur[Nt * 4 + 3];
        Bhi[Nt] = U.h;
        Blo[Nt] = V.h;
      }
#pragma unroll
      for (int Mt = 0; Mt < 2; ++Mt)
#pragma unroll
        for (int Nt = 0; Nt < 2; ++Nt) {
          acch[Mt][Nt] = __builtin_amdgcn_mfma_f32_16x16x32_f16(
              whi[Mt][Kt], Bhi[Nt], acch[Mt][Nt], 0, 0, 0);
          accl[Mt][Nt] = __builtin_amdgcn_mfma_f32_16x16x32_f16(
              whi[Mt][Kt], Blo[Nt], accl[Mt][Nt], 0, 0, 0);
          accl[Mt][Nt] = __builtin_amdgcn_mfma_f32_16x16x32_f16(
              wlo[Mt][Kt], Bhi[Nt], accl[Mt][Nt], 0, 0, 0);
        }
#pragma unroll
      for (int e = 0; e < 8; ++e) cur[e] = nxt[e];
    }

    // gates -> gl ; C/D layout: col=lane&15, row=(lane>>4)*4+reg
#pragma unroll
    for (int Mt = 0; Mt < 2; ++Mt)
#pragma unroll
      for (int Nt = 0; Nt < 2; ++Nt)
#pragma unroll
        for (int r = 0; r < 4; ++r) {
          int ul = Mt * 16 + lq * 4 + r;
          gl[(w * 32 + ul) * 33 + Nt * 16 + lx] =
              acch[Mt][Nt][r] + accl[Mt][Nt][r] * inv2048;
        }
    __syncthreads();   // (A) gl ready; also protects ps WAR from previous step's publish reads

    // cell update; stage publish words into ps (slab order)
    float* hb = hbuf + (size_t)(d * (S_ + 1) + t + 1) * (H_ * B_) + u0 * B_;
#pragma unroll
    for (int cu = 0; cu < 4; ++cu) {
      int u = cu * 8 + cw;
      float g_i = gl[(0 * 32 + u) * 33 + bc];
      float g_f = gl[(1 * 32 + u) * 33 + bc];
      float g_g = gl[(2 * 32 + u) * 33 + bc];
      float g_o = gl[(3 * 32 + u) * 33 + bc];
      float si = 1.f / (1.f + expf(-g_i));
      float sf = 1.f / (1.f + expf(-g_f));
      float so = 1.f / (1.f + expf(-g_o));
      float tg = tanhf(g_g);
      float cn = sf * creg[cu] + si * tg;
      float hn = so * tanhf(cn);
      creg[cu] = cn;
      hb[cu * 256 + tid] = hn;  // coalesced fp32 [k][b]
      unsigned me = pack_split(hn);
      unsigned pa = (unsigned)__shfl_xor((int)me, 32, 64);  // partner cw^1 (same bc,cu)
      unsigned je = (cw & 1) ? pa : me;
      unsigned jo = (cw & 1) ? me : pa;
      unsigned hiw = (je & 0xFFFFu) | (jo << 16);
      unsigned low = (je >> 16) | (jo & 0xFFFF0000u);
      int lane = (cu << 4) | (bc & 15);
      int m8 = phi ? pm : (4 + pm);
      ps[pNt * 512 + lane * 8 + m8] = phi ? hiw : low;
    }
    __syncthreads();   // (B) ps complete

    // coalesced publish: 2 contiguous u64 agent-atomic stores per thread.
    // Drain overlaps next step's poll (no barrier between here and the poll).
    {
      unsigned long long* slab64 =
          (unsigned long long*)(hfrag + (size_t)(d * (S_ + 1) + t + 1) * SLAB_);
      const unsigned long long* psq = (const unsigned long long*)ps;
      unsigned long long v0 = psq[tid];
      unsigned long long v1 = psq[tid + 256];
      __hip_atomic_store(&slab64[(size_t)(0 * 8 + iblk) * 256 + tid], v0,
                         __ATOMIC_RELAXED, __HIP_MEMORY_SCOPE_AGENT);
      __hip_atomic_store(&slab64[(size_t)(1 * 8 + iblk) * 256 + tid], v1,
                         __ATOMIC_RELAXED, __HIP_MEMORY_SCOPE_AGENT);
    }
  }
}

// ---------------------------------------------------------------- FC -> emissions em[b][s][l]
__global__ void k_fc(const float* __restrict__ hbuf, const float* __restrict__ fc_w,
                     const float* __restrict__ fc_b, float* __restrict__ em) {
  int idx = blockIdx.x * 256 + threadIdx.x;
  if (idx >= B_ * S_ * L_) return;
  int l = idx % L_;
  int bs = idx / L_;
  int s = bs % S_;
  int b = bs / S_;
  const float* hf = hbuf + ((size_t)(s + 1)) * (H_ * B_);
  const float* hb = hbuf + ((size_t)(S_ + 1) + (S_ - s)) * ((size_t)H_ * B_);
  const float* w = fc_w + (size_t)l * (2 * H_);
  float acc = fc_b[l];
  for (int k = 0; k < H_; ++k) acc = fmaf(hf[k * B_ + b], w[k], acc);
  for (int k = 0; k < H_; ++k) acc = fmaf(hb[k * B_ + b], w[H_ + k], acc);
  em[(size_t)idx] = acc;
}

// ---------------------------------------------------------------- softmax over SEQ dim (faithful)
__global__ void k_softmax(float* __restrict__ em) {
  int b = blockIdx.x;
  __shared__ float e[S_ * L_];
  int tid = threadIdx.x;
  for (int i = tid; i < S_ * L_; i += 256) e[i] = em[(size_t)b * S_ * L_ + i];
  __syncthreads();
  if (tid < L_) {
    int l = tid;
    float m = -INFINITY;
    for (int s = 0; s < S_; ++s) m = fmaxf(m, e[s * L_ + l]);
    float sum = 0.f;
    for (int s = 0; s < S_; ++s) {
      float ex = expf(e[s * L_ + l] - m);
      e[s * L_ + l] = ex;
      sum += ex;
    }
    for (int s = 0; s < S_; ++s) e[s * L_ + l] = e[s * L_ + l] / sum;
  }
  __syncthreads();
  for (int i = tid; i < S_ * L_; i += 256) em[(size_t)b * S_ * L_ + i] = e[i];
}

// ---------------------------------------------------------------- Viterbi (one block per batch)
__global__ void k_viterbi(const float* __restrict__ em, const int* __restrict__ x,
                          const float* __restrict__ start_t, const float* __restrict__ trans,
                          const float* __restrict__ end_t, int* __restrict__ hist,
                          int* __restrict__ out) {
  int b = blockIdx.x;
  __shared__ float tr[L_ * L_];
  __shared__ float sc[2][L_];
  int tid = threadIdx.x;
  for (int i = tid; i < L_ * L_; i += 64) tr[i] = trans[i];
  if (tid < L_) sc[0][tid] = start_t[tid] + em[((size_t)b * S_ + 0) * L_ + tid];
  __syncthreads();
  int cbuf = 0;
  for (int t = 1; t < S_; ++t) {
    if (tid < L_) {
      int j = tid;
      float e = em[((size_t)b * S_ + t) * L_ + j];
      float best = -INFINITY;
      int arg = 0;
      for (int i = 0; i < L_; ++i) {
        float v = (sc[cbuf][i] + tr[i * L_ + j]) + e;
        if (v > best) { best = v; arg = i; }  // strict >: first occurrence like np.argmax
      }
      int maskt = (x[b * S_ + t] != 0);
      sc[cbuf ^ 1][j] = maskt ? best : sc[cbuf][j];
      hist[((size_t)(t - 1) * B_ + b) * L_ + j] = arg;
    }
    __syncthreads();
    cbuf ^= 1;
  }
  __syncthreads();
  if (tid == 0) {
    float best = -INFINITY;
    int last = 0;
    for (int j = 0; j < L_; ++j) {
      float v = sc[cbuf][j] + end_t[j];
      if (v > best) { best = v; last = j; }
    }
    int cur = last;
    out[b * S_ + S_ - 1] = cur;
    for (int p = S_ - 2; p >= 0; --p) {
      if (x[b * S_ + p + 1] != 0) cur = hist[((size_t)p * B_ + b) * L_ + cur];
      out[b * S_ + p] = cur;
    }
  }
}

// ---------------------------------------------------------------- launch
extern "C" void kernel_launch(void* const* d_in, const int* in_sizes, int n_in,
                              void* d_out, int out_size, void* d_ws, size_t ws_size,
                              hipStream_t stream) {
  const int* x        = (const int*)d_in[0];
  const int* x_char   = (const int*)d_in[1];
  const float* word_emb = (const float*)d_in[2];
  const float* char_emb = (const float*)d_in[3];
  const float* conv1_w = (const float*)d_in[4];
  const float* conv1_b = (const float*)d_in[5];
  const float* conv2_w = (const float*)d_in[6];
  const float* conv2_b = (const float*)d_in[7];
  const float* conv3_w = (const float*)d_in[8];
  const float* conv3_b = (const float*)d_in[9];
  const float* w_ih_f = (const float*)d_in[10];
  const float* w_hh_f = (const float*)d_in[11];
  const float* b_f    = (const float*)d_in[12];
  const float* w_ih_b = (const float*)d_in[13];
  const float* w_hh_b = (const float*)d_in[14];
  const float* b_b    = (const float*)d_in[15];
  const float* h0     = (const float*)d_in[16];
  const float* c0     = (const float*)d_in[17];
  const float* fc_w   = (const float*)d_in[18];
  const float* fc_b   = (const float*)d_in[19];
  const float* start_t = (const float*)d_in[20];
  const float* trans  = (const float*)d_in[21];
  const float* end_t  = (const float*)d_in[22];
  int* out = (int*)d_out;

  char* ws = (char*)d_ws;
  auto alloc = [&](size_t bytes) -> char* {
    char* p = ws;
    ws += (bytes + 1023) & ~(size_t)1023;
    return p;
  };
  float* pooled  = (float*)alloc(sizeof(float) * B_ * C_);
  float* biaseff = (float*)alloc(sizeof(float) * 2 * G4_ * B_);
  float* gi      = (float*)alloc(sizeof(float) * 2 * S_ * G4_ * B_);          // 33.5 MB
  float* hbuf    = (float*)alloc(sizeof(float) * 2 * (S_ + 1) * H_ * B_);     // 8.45 MB
  unsigned* hfrag = (unsigned*)alloc(sizeof(unsigned) * 2 * (S_ + 1) * SLAB_); // 8.45 MB
  float* out1    = (float*)alloc(sizeof(float) * B_ * C_ * 48);
  float* out2    = (float*)alloc(sizeof(float) * B_ * C_ * 45);
  float* em      = (float*)alloc(sizeof(float) * B_ * S_ * L_);
  int* hist      = (int*)alloc(sizeof(int) * (S_ - 1) * B_ * L_);

  const int hinit_total = 2 * (S_ + 1) * SLAB_;
  k_hinit<<<(hinit_total + 255) / 256, 256, 0, stream>>>(h0, hfrag);
  k_conv1<<<dim3(32, 2), 256, 0, stream>>>(x_char, char_emb, conv1_w, conv1_b, out1);
  k_conv2<<<dim3(32, 4), 256, 0, stream>>>(out1, conv2_w, conv2_b, out2);
  k_conv3<<<dim3(32, 5), 256, 0, stream>>>(out2, conv3_w, conv3_b, pooled);
  k_biaseff<<<dim3(32, 2), 256, 0, stream>>>(pooled, w_ih_f, b_f, w_ih_b, b_b, biaseff);
  k_gemm_in<<<dim3(8, 32, 2), 256, 0, stream>>>(x, word_emb, w_ih_f, w_ih_b, biaseff, gi);
  k_lstm<<<dim3(NBLKD, 2), 256, 0, stream>>>(w_hh_f, w_hh_b, c0, gi, hbuf, hfrag);
  k_fc<<<(B_ * S_ * L_ + 255) / 256, 256, 0, stream>>>(hbuf, fc_w, fc_b, em);
  k_softmax<<<32, 256, 0, stream>>>(em);
  k_viterbi<<<32, 64, 0, stream>>>(em, x, start_t, trans, end_t, hist, out);
}

// Round 6
// 1052.190 us; speedup vs baseline: 1.7214x; 1.4114x over previous
//
#include <hip/hip_runtime.h>
#include <cmath>

#define B_   32
#define S_   128
#define E_   300
#define C_   100
#define EC_  50
#define LC_  50
#define H_   256
#define G4_  1024   // 4*H
#define L_   17
#define DHID_ 400   // E + C
#define NBLKD 8     // lstm blocks per direction
#define SLAB_ 8192  // u32 per (d,t) frag slab: [Nt(2)][Kt(8)][lane(64)][hi m0..3 | lo m4..7]
#define SENT2_ 0x7E007E00u  // fp16-NaN in both halves: legit packed pair never matches

typedef _Float16 half8 __attribute__((ext_vector_type(8)));
typedef float f32x4 __attribute__((ext_vector_type(4)));
typedef unsigned long long ull;
struct __align__(16) U2 { ull x, y; };

// split fp32 -> (hi fp16, lo fp16 scaled by 2048), packed u32 (hi in low16).
__device__ __forceinline__ unsigned pack_split(float v) {
  _Float16 hi = (fabsf(v) >= 6.104e-5f) ? (_Float16)v : (_Float16)0.0f;
  float hif = (float)hi;
  _Float16 lo = (_Float16)((v - hif) * 2048.0f);
  return (unsigned)__builtin_bit_cast(unsigned short, hi)
       | ((unsigned)__builtin_bit_cast(unsigned short, lo) << 16);
}

// ---------------------------------------------------------------- hfrag init: t=0 from h0, t>=1 sentinel
__global__ void k_hinit(const float* __restrict__ h0, unsigned* __restrict__ hfrag) {
  int idx = blockIdx.x * 256 + threadIdx.x;
  const int total = 2 * (S_ + 1) * SLAB_;
  if (idx >= total) return;
  int sd = idx / SLAB_;           // d*(S+1)+t
  int within = idx % SLAB_;
  int t = sd % (S_ + 1), d = sd / (S_ + 1);
  if (t != 0) { hfrag[idx] = SENT2_; return; }
  int m8 = within & 7;            // 0-3 hi words, 4-7 lo words
  int lane = (within >> 3) & 63;
  int q = within >> 9;            // Nt*8+Kt
  int Kt = q & 7, Nt = q >> 3;
  int m = m8 & 3, isLo = m8 >> 2;
  int k0 = Kt * 32 + (lane >> 4) * 8 + 2 * m;
  int b = Nt * 16 + (lane & 15);
  unsigned p0 = pack_split(h0[((size_t)d * B_ + b) * H_ + k0]);
  unsigned p1 = pack_split(h0[((size_t)d * B_ + b) * H_ + k0 + 1]);
  unsigned hiw = (p0 & 0xFFFFu) | (p1 << 16);
  unsigned low = (p0 >> 16) | (p1 & 0xFFFF0000u);
  hfrag[idx] = isLo ? low : hiw;
}

// ---------------------------------------------------------------- char conv1
__global__ void k_conv1(const int* __restrict__ x_char, const float* __restrict__ char_emb,
                        const float* __restrict__ w1, const float* __restrict__ b1,
                        float* __restrict__ out1) {
  int b = blockIdx.x;
  int ot = blockIdx.y;
  __shared__ float ce[EC_ * 52];
  __shared__ float wl[50 * 150];
  __shared__ int ids[LC_];
  int tid = threadIdx.x;
  if (tid < LC_) ids[tid] = x_char[b * LC_ + tid];
  __syncthreads();
  for (int idx = tid; idx < LC_ * EC_; idx += 256) {
    int t = idx / EC_, ec = idx % EC_;
    ce[ec * 52 + t] = char_emb[ids[t] * EC_ + ec];
  }
  int obase = ot * 50;
  for (int idx = tid; idx < 50 * 150; idx += 256)
    wl[idx] = w1[obase * 150 + idx];
  __syncthreads();
  for (int idx = tid; idx < 50 * 48; idx += 256) {
    int o = idx / 48, t = idx % 48;
    float acc = b1[obase + o];
    const float* wr = &wl[o * 150];
    for (int c = 0; c < EC_; ++c) {
      const float* ip = &ce[c * 52 + t];
      acc += wr[c * 3 + 0] * ip[0] + wr[c * 3 + 1] * ip[1] + wr[c * 3 + 2] * ip[2];
    }
    out1[((size_t)b * C_ + obase + o) * 48 + t] = fmaxf(acc, 0.0f);
  }
}

// ---------------------------------------------------------------- char conv2
__global__ void k_conv2(const float* __restrict__ in, const float* __restrict__ w2,
                        const float* __restrict__ b2, float* __restrict__ out2) {
  int b = blockIdx.x, ot = blockIdx.y;
  __shared__ float il[C_ * 48];
  __shared__ float wl[25 * 400];
  int tid = threadIdx.x;
  for (int idx = tid; idx < C_ * 48; idx += 256) il[idx] = in[(size_t)b * C_ * 48 + idx];
  int obase = ot * 25;
  for (int idx = tid; idx < 25 * 400; idx += 256) wl[idx] = w2[obase * 400 + idx];
  __syncthreads();
  for (int idx = tid; idx < 25 * 45; idx += 256) {
    int o = idx / 45, t = idx % 45;
    float acc = b2[obase + o];
    const float* wr = &wl[o * 400];
    for (int c = 0; c < C_; ++c) {
      const float* ip = &il[c * 48 + t];
      acc += wr[c * 4 + 0] * ip[0] + wr[c * 4 + 1] * ip[1] +
             wr[c * 4 + 2] * ip[2] + wr[c * 4 + 3] * ip[3];
    }
    out2[((size_t)b * C_ + obase + o) * 45 + t] = fmaxf(acc, 0.0f);
  }
}

// ---------------------------------------------------------------- char conv3 + maxpool
__global__ void k_conv3(const float* __restrict__ in, const float* __restrict__ w3,
                        const float* __restrict__ b3, float* __restrict__ pooled) {
  int b = blockIdx.x, ot = blockIdx.y;
  __shared__ float il[C_ * 45];
  __shared__ float wl[20 * 500];
  __shared__ float o3[20 * 44];
  int tid = threadIdx.x;
  for (int idx = tid; idx < C_ * 45; idx += 256) il[idx] = in[(size_t)b * C_ * 45 + idx];
  int obase = ot * 20;
  for (int idx = tid; idx < 20 * 500; idx += 256) wl[idx] = w3[obase * 500 + idx];
  __syncthreads();
  for (int idx = tid; idx < 20 * 41; idx += 256) {
    int o = idx / 41, t = idx % 41;
    float acc = b3[obase + o];
    const float* wr = &wl[o * 500];
    for (int c = 0; c < C_; ++c) {
      const float* ip = &il[c * 45 + t];
      acc += wr[c * 5 + 0] * ip[0] + wr[c * 5 + 1] * ip[1] + wr[c * 5 + 2] * ip[2] +
             wr[c * 5 + 3] * ip[3] + wr[c * 5 + 4] * ip[4];
    }
    o3[o * 44 + t] = fmaxf(acc, 0.0f);
  }
  __syncthreads();
  if (tid < 20) {
    float m = o3[tid * 44];
    for (int t = 1; t < 41; ++t) m = fmaxf(m, o3[tid * 44 + t]);
    pooled[b * C_ + obase + tid] = m;
  }
}

// ---------------------------------------------------------------- effective bias -> [d][j][b]
__global__ void k_biaseff(const float* __restrict__ pooled,
                          const float* __restrict__ w_ih_f, const float* __restrict__ b_f,
                          const float* __restrict__ w_ih_b, const float* __restrict__ b_b,
                          float* __restrict__ biaseff) {
  int b = blockIdx.x, d = blockIdx.y;
  const float* wih = d ? w_ih_b : w_ih_f;
  const float* bb = d ? b_b : b_f;
  __shared__ float pl[C_];
  int tid = threadIdx.x;
  if (tid < C_) pl[tid] = pooled[b * C_ + tid];
  __syncthreads();
  for (int j = tid; j < G4_; j += 256) {
    float acc = bb[j];
    const float* wr = &wih[(size_t)j * DHID_ + E_];
    for (int c = 0; c < C_; ++c) acc += pl[c] * wr[c];
    biaseff[((size_t)d * G4_ + j) * B_ + b] = acc;
  }
}

// ---------------------------------------------------------------- input GEMM -> gi[d][t][j][b]
__global__ __launch_bounds__(256) void k_gemm_in(
    const int* __restrict__ x, const float* __restrict__ word_emb,
    const float* __restrict__ w_ih_f, const float* __restrict__ w_ih_b,
    const float* __restrict__ biaseff, float* __restrict__ gi) {
  int jt = blockIdx.x;
  int rt = blockIdx.y;
  int d = blockIdx.z;
  const float* wih = d ? w_ih_b : w_ih_f;
  __shared__ float Al[16][132];
  __shared__ float Bl[16][132];
  __shared__ int wid[128];
  int tid = threadIdx.x;
  int r0 = rt * 128, j0 = jt * 128;
  if (tid < 128) {
    int r = r0 + tid;
    int t = r >> 5, b = r & 31;
    wid[tid] = x[b * S_ + t];
  }
  __syncthreads();
  float acc[8][8];
#pragma unroll
  for (int i = 0; i < 8; ++i)
#pragma unroll
    for (int j = 0; j < 8; ++j) acc[i][j] = 0.f;
  int ty = tid >> 4, tx = tid & 15;

  for (int k0 = 0; k0 < 304; k0 += 16) {
#pragma unroll
    for (int i = 0; i < 2; ++i) {
      int f = tid + i * 256;
      int rl = f >> 2, kc = f & 3;
      const float* src = word_emb + (size_t)wid[rl] * E_;
#pragma unroll
      for (int e = 0; e < 4; ++e) {
        int k = k0 + kc * 4 + e;
        float v = src[k < E_ ? k : (E_ - 1)];
        Al[kc * 4 + e][rl] = (k < E_) ? v : 0.f;
      }
    }
#pragma unroll
    for (int i = 0; i < 2; ++i) {
      int f = tid + i * 256;
      int jl = f >> 2, kc = f & 3;
      const float* src = wih + (size_t)(j0 + jl) * DHID_;
#pragma unroll
      for (int e = 0; e < 4; ++e) {
        int k = k0 + kc * 4 + e;
        float v = src[k];
        Bl[kc * 4 + e][jl] = (k < E_) ? v : 0.f;
      }
    }
    __syncthreads();
#pragma unroll
    for (int kk = 0; kk < 16; ++kk) {
      float4 a0 = *(const float4*)(&Al[kk][ty * 8]);
      float4 a1 = *(const float4*)(&Al[kk][ty * 8 + 4]);
      float4 b0 = *(const float4*)(&Bl[kk][tx * 8]);
      float4 b1 = *(const float4*)(&Bl[kk][tx * 8 + 4]);
      float av[8] = {a0.x, a0.y, a0.z, a0.w, a1.x, a1.y, a1.z, a1.w};
      float bv[8] = {b0.x, b0.y, b0.z, b0.w, b1.x, b1.y, b1.z, b1.w};
#pragma unroll
      for (int i = 0; i < 8; ++i)
#pragma unroll
        for (int j = 0; j < 8; ++j) acc[i][j] = fmaf(av[i], bv[j], acc[i][j]);
    }
    __syncthreads();
  }
  int b0 = (ty & 3) * 8;
  int tt = rt * 4 + (ty >> 2);
#pragma unroll
  for (int jj = 0; jj < 8; ++jj) {
    int j = j0 + tx * 8 + jj;
    const float* be = biaseff + ((size_t)d * G4_ + j) * B_ + b0;
    float4 bl = *(const float4*)(be);
    float4 bh = *(const float4*)(be + 4);
    float4 lo, hi;
    lo.x = acc[0][jj] + bl.x; lo.y = acc[1][jj] + bl.y;
    lo.z = acc[2][jj] + bl.z; lo.w = acc[3][jj] + bl.w;
    hi.x = acc[4][jj] + bh.x; hi.y = acc[5][jj] + bh.y;
    hi.z = acc[6][jj] + bh.z; hi.w = acc[7][jj] + bh.w;
    float* dst = gi + (((size_t)(d * S_ + tt) * G4_) + j) * B_ + b0;
    *(float4*)dst = lo;
    *(float4*)(dst + 4) = hi;
  }
}

// ---------------------------------------------------------------- BiLSTM recurrence via MFMA fp16x2
// grid (NBLKD, 2); block 256 (4 waves), wave = gate. Block iblk owns u in [iblk*32,+32) == K-tile Kt=iblk.
// R6 consume: wave w bulk-polls ONLY its quarter of the slab (chunks q=w*4..w*4+3; 16 u64/thread,
// all in flight, one L3 round per retry), stages to LDS (slh/sll, 16B/lane stride = conflict-free),
// barrier, all waves read frags via b128. 4x less poll traffic, 32 poll VGPRs, no per-chunk serial rounds.
// R6 publish: unchanged coalesced 2xu64/thread (R5), ps staging stride-9 padded (kills 8-way conflicts),
// publish stores issued before hbuf write.
__global__ __launch_bounds__(256, 1) void k_lstm(
    const float* __restrict__ w_hh_f, const float* __restrict__ w_hh_b,
    const float* __restrict__ c0, const float* __restrict__ gi,
    float* __restrict__ hbuf, unsigned* __restrict__ hfrag) {
  const int iblk = blockIdx.x;     // 0..7
  const int d = blockIdx.y;
  const float* whh = d ? w_hh_b : w_hh_f;
  const int tid = threadIdx.x;
  const int w = tid >> 6;          // wave index = gate (i,f,g,o)
  const int l = tid & 63;
  const int lx = l & 15, lq = l >> 4;
  const int u0 = iblk * 32;

  __shared__ ull slh[2048];                       // hi-pair u64s, frag order (16 KB)
  __shared__ ull sll[2048];                       // lo-pair u64s (16 KB)
  __shared__ float gl[4 * 32 * 33];               // [gate][u][b] (16.9 KB)
  __shared__ unsigned ps[2 * 576];                // publish staging, stride-9 padded (4.6 KB)

  // ---- persistent W fragments: A[m=lane&15][k=(lane>>4)*8+j]
  half8 whi[2][8], wlo[2][8];
#pragma unroll
  for (int Mt = 0; Mt < 2; ++Mt) {
#pragma unroll
    for (int Kt = 0; Kt < 8; ++Kt) {
      int row = w * H_ + u0 + Mt * 16 + lx;
      int kk0 = Kt * 32 + lq * 8;
      const float* src = whh + (size_t)row * H_ + kk0;
      float4 f0 = *(const float4*)src;
      float4 f1 = *(const float4*)(src + 4);
      float wv[8] = {f0.x, f0.y, f0.z, f0.w, f1.x, f1.y, f1.z, f1.w};
      union { unsigned short s[8]; half8 h; } HI, LO;
#pragma unroll
      for (int j = 0; j < 8; ++j) {
        float v = wv[j];
        _Float16 hi = (fabsf(v) >= 6.104e-5f) ? (_Float16)v : (_Float16)0.0f;
        float hif = (float)hi;
        _Float16 lo = (_Float16)((v - hif) * 2048.0f);
        HI.s[j] = __builtin_bit_cast(unsigned short, hi);
        LO.s[j] = __builtin_bit_cast(unsigned short, lo);
      }
      whi[Mt][Kt] = HI.h;
      wlo[Mt][Kt] = LO.h;
    }
  }

  // cell state: thread (bc = tid&31, cw = tid>>5 in 0..7) owns u = cu*8+cw
  const int bc = tid & 31, cw = tid >> 5;
  float creg[4];
#pragma unroll
  for (int cu = 0; cu < 4; ++cu)
    creg[cu] = c0[((size_t)d * B_ + bc) * H_ + u0 + cu * 8 + cw];

  const int pNt = bc >> 4;
  const int pm = cw >> 1;
  const bool phi = (cw & 1) == 0;
  const int plane = bc & 15;       // low 4 bits of frag lane
  const float inv2048 = 1.0f / 2048.0f;

  for (int t = 0; t < S_; ++t) {
    int torig = d ? (S_ - 1 - t) : t;

    // gate-input frags (independent of h): init acc_hi with gi (C-operand trick)
    f32x4 acch[2][2], accl[2][2];
    {
      const float* gbase = gi + ((size_t)(d * S_ + torig) * G4_) * B_;
#pragma unroll
      for (int Mt = 0; Mt < 2; ++Mt)
#pragma unroll
        for (int Nt = 0; Nt < 2; ++Nt) {
          f32x4 v;
#pragma unroll
          for (int r = 0; r < 4; ++r) {
            int j = w * H_ + u0 + Mt * 16 + lq * 4 + r;
            v[r] = gbase[(size_t)j * B_ + Nt * 16 + lx];
          }
          acch[Mt][Nt] = v;
          f32x4 z = {0.f, 0.f, 0.f, 0.f};
          accl[Mt][Nt] = z;
        }
    }

    // bulk poll: wave w owns chunks q = w*4 .. w*4+3 (16 u64/thread, all in flight)
    const ull* hp = (const ull*)(hfrag + (size_t)(d * (S_ + 1) + t) * SLAB_);
    ull pv[4][4];
#pragma unroll
    for (int c = 0; c < 4; ++c) {
      size_t base = ((size_t)(w * 4 + c) * 64 + l) * 4;
#pragma unroll
      for (int j = 0; j < 4; ++j)
        pv[c][j] = __hip_atomic_load(&hp[base + j], __ATOMIC_RELAXED,
                                     __HIP_MEMORY_SCOPE_AGENT);
    }
    for (;;) {
      bool pending = false;
#pragma unroll
      for (int c = 0; c < 4; ++c)
#pragma unroll
        for (int j = 0; j < 4; ++j)
          pending |= ((unsigned)pv[c][j] == SENT2_) |
                     ((unsigned)(pv[c][j] >> 32) == SENT2_);
      if (!pending) break;
#pragma unroll
      for (int c = 0; c < 4; ++c) {
        size_t base = ((size_t)(w * 4 + c) * 64 + l) * 4;
#pragma unroll
        for (int j = 0; j < 4; ++j)
          pv[c][j] = __hip_atomic_load(&hp[base + j], __ATOMIC_RELAXED,
                                       __HIP_MEMORY_SCOPE_AGENT);
      }
    }
    // stage to LDS in frag order (16 B/lane stride -> conflict-free b128)
#pragma unroll
    for (int c = 0; c < 4; ++c) {
      int idx = ((w * 4 + c) * 64 + l) * 2;
      U2 vh; vh.x = pv[c][0]; vh.y = pv[c][1];
      U2 vl; vl.x = pv[c][2]; vl.y = pv[c][3];
      *(U2*)&slh[idx] = vh;
      *(U2*)&sll[idx] = vl;
    }
    __syncthreads();   // (1) slab LDS complete

    // MFMA over Kt, frags straight from LDS (b128, conflict-free)
#pragma unroll
    for (int Kt = 0; Kt < 8; ++Kt) {
      half8 Bhi[2], Blo[2];
#pragma unroll
      for (int Nt = 0; Nt < 2; ++Nt) {
        int idx = ((Nt * 8 + Kt) * 64 + l) * 2;
        union { U2 u; half8 h; } UH, UL;
        UH.u = *(const U2*)&slh[idx];
        UL.u = *(const U2*)&sll[idx];
        Bhi[Nt] = UH.h;
        Blo[Nt] = UL.h;
      }
#pragma unroll
      for (int Mt = 0; Mt < 2; ++Mt)
#pragma unroll
        for (int Nt = 0; Nt < 2; ++Nt) {
          acch[Mt][Nt] = __builtin_amdgcn_mfma_f32_16x16x32_f16(
              whi[Mt][Kt], Bhi[Nt], acch[Mt][Nt], 0, 0, 0);
          accl[Mt][Nt] = __builtin_amdgcn_mfma_f32_16x16x32_f16(
              whi[Mt][Kt], Blo[Nt], accl[Mt][Nt], 0, 0, 0);
          accl[Mt][Nt] = __builtin_amdgcn_mfma_f32_16x16x32_f16(
              wlo[Mt][Kt], Bhi[Nt], accl[Mt][Nt], 0, 0, 0);
        }
    }

    // gates -> gl ; C/D layout: col=lane&15, row=(lane>>4)*4+reg
#pragma unroll
    for (int Mt = 0; Mt < 2; ++Mt)
#pragma unroll
      for (int Nt = 0; Nt < 2; ++Nt)
#pragma unroll
        for (int r = 0; r < 4; ++r) {
          int ul = Mt * 16 + lq * 4 + r;
          gl[(w * 32 + ul) * 33 + Nt * 16 + lx] =
              acch[Mt][Nt][r] + accl[Mt][Nt][r] * inv2048;
        }
    __syncthreads();   // (2) gl ready

    // cell update; stage publish words into padded ps
    float hreg[4];
#pragma unroll
    for (int cu = 0; cu < 4; ++cu) {
      int u = cu * 8 + cw;
      float g_i = gl[(0 * 32 + u) * 33 + bc];
      float g_f = gl[(1 * 32 + u) * 33 + bc];
      float g_g = gl[(2 * 32 + u) * 33 + bc];
      float g_o = gl[(3 * 32 + u) * 33 + bc];
      float si = 1.f / (1.f + __expf(-g_i));
      float sf = 1.f / (1.f + __expf(-g_f));
      float so = 1.f / (1.f + __expf(-g_o));
      float tg = 1.f - 2.f / (__expf(2.f * g_g) + 1.f);
      float cn = sf * creg[cu] + si * tg;
      float tc = 1.f - 2.f / (__expf(2.f * cn) + 1.f);
      float hn = so * tc;
      creg[cu] = cn;
      hreg[cu] = hn;
      unsigned me = pack_split(hn);
      unsigned pa = (unsigned)__shfl_xor((int)me, 32, 64);  // partner cw^1 (same bc,cu)
      unsigned je = (cw & 1) ? pa : me;
      unsigned jo = (cw & 1) ? me : pa;
      unsigned hiw = (je & 0xFFFFu) | (jo << 16);
      unsigned low = (je >> 16) | (jo & 0xFFFF0000u);
      int lane2 = (cu << 4) | plane;
      int m8 = phi ? pm : (4 + pm);
      ps[pNt * 576 + lane2 * 9 + m8] = phi ? hiw : low;
    }
    __syncthreads();   // (3) ps complete

    // coalesced publish first (latency-critical), then hbuf
    {
      ull* slab64 = (ull*)(hfrag + (size_t)(d * (S_ + 1) + t + 1) * SLAB_);
#pragma unroll
      for (int hh = 0; hh < 2; ++hh) {
        int r = tid;                      // u64 index within Nt-half
        int Nt = hh;
        int lane2 = r >> 2, m2 = r & 3;
        unsigned a = ps[Nt * 576 + lane2 * 9 + 2 * m2];
        unsigned b = ps[Nt * 576 + lane2 * 9 + 2 * m2 + 1];
        ull v = (ull)a | ((ull)b << 32);
        __hip_atomic_store(&slab64[(size_t)(Nt * 8 + iblk) * 256 + r], v,
                           __ATOMIC_RELAXED, __HIP_MEMORY_SCOPE_AGENT);
      }
      float* hb = hbuf + (size_t)(d * (S_ + 1) + t + 1) * (H_ * B_) + u0 * B_;
#pragma unroll
      for (int cu = 0; cu < 4; ++cu) hb[cu * 256 + tid] = hreg[cu];
    }
  }
}

// ---------------------------------------------------------------- FC -> emissions em[b][s][l]
__global__ void k_fc(const float* __restrict__ hbuf, const float* __restrict__ fc_w,
                     const float* __restrict__ fc_b, float* __restrict__ em) {
  int idx = blockIdx.x * 256 + threadIdx.x;
  if (idx >= B_ * S_ * L_) return;
  int l = idx % L_;
  int bs = idx / L_;
  int s = bs % S_;
  int b = bs / S_;
  const float* hf = hbuf + ((size_t)(s + 1)) * (H_ * B_);
  const float* hb = hbuf + ((size_t)(S_ + 1) + (S_ - s)) * ((size_t)H_ * B_);
  const float* w = fc_w + (size_t)l * (2 * H_);
  float acc = fc_b[l];
  for (int k = 0; k < H_; ++k) acc = fmaf(hf[k * B_ + b], w[k], acc);
  for (int k = 0; k < H_; ++k) acc = fmaf(hb[k * B_ + b], w[H_ + k], acc);
  em[(size_t)idx] = acc;
}

// ---------------------------------------------------------------- softmax over SEQ dim (faithful)
__global__ void k_softmax(float* __restrict__ em) {
  int b = blockIdx.x;
  __shared__ float e[S_ * L_];
  int tid = threadIdx.x;
  for (int i = tid; i < S_ * L_; i += 256) e[i] = em[(size_t)b * S_ * L_ + i];
  __syncthreads();
  if (tid < L_) {
    int l = tid;
    float m = -INFINITY;
    for (int s = 0; s < S_; ++s) m = fmaxf(m, e[s * L_ + l]);
    float sum = 0.f;
    for (int s = 0; s < S_; ++s) {
      float ex = expf(e[s * L_ + l] - m);
      e[s * L_ + l] = ex;
      sum += ex;
    }
    for (int s = 0; s < S_; ++s) e[s * L_ + l] = e[s * L_ + l] / sum;
  }
  __syncthreads();
  for (int i = tid; i < S_ * L_; i += 256) em[(size_t)b * S_ * L_ + i] = e[i];
}

// ---------------------------------------------------------------- Viterbi (one block per batch)
__global__ void k_viterbi(const float* __restrict__ em, const int* __restrict__ x,
                          const float* __restrict__ start_t, const float* __restrict__ trans,
                          const float* __restrict__ end_t, int* __restrict__ hist,
                          int* __restrict__ out) {
  int b = blockIdx.x;
  __shared__ float tr[L_ * L_];
  __shared__ float sc[2][L_];
  int tid = threadIdx.x;
  for (int i = tid; i < L_ * L_; i += 64) tr[i] = trans[i];
  if (tid < L_) sc[0][tid] = start_t[tid] + em[((size_t)b * S_ + 0) * L_ + tid];
  __syncthreads();
  int cbuf = 0;
  for (int t = 1; t < S_; ++t) {
    if (tid < L_) {
      int j = tid;
      float e = em[((size_t)b * S_ + t) * L_ + j];
      float best = -INFINITY;
      int arg = 0;
      for (int i = 0; i < L_; ++i) {
        float v = (sc[cbuf][i] + tr[i * L_ + j]) + e;
        if (v > best) { best = v; arg = i; }  // strict >: first occurrence like np.argmax
      }
      int maskt = (x[b * S_ + t] != 0);
      sc[cbuf ^ 1][j] = maskt ? best : sc[cbuf][j];
      hist[((size_t)(t - 1) * B_ + b) * L_ + j] = arg;
    }
    __syncthreads();
    cbuf ^= 1;
  }
  __syncthreads();
  if (tid == 0) {
    float best = -INFINITY;
    int last = 0;
    for (int j = 0; j < L_; ++j) {
      float v = sc[cbuf][j] + end_t[j];
      if (v > best) { best = v; last = j; }
    }
    int cur = last;
    out[b * S_ + S_ - 1] = cur;
    for (int p = S_ - 2; p >= 0; --p) {
      if (x[b * S_ + p + 1] != 0) cur = hist[((size_t)p * B_ + b) * L_ + cur];
      out[b * S_ + p] = cur;
    }
  }
}

// ---------------------------------------------------------------- launch
extern "C" void kernel_launch(void* const* d_in, const int* in_sizes, int n_in,
                              void* d_out, int out_size, void* d_ws, size_t ws_size,
                              hipStream_t stream) {
  const int* x        = (const int*)d_in[0];
  const int* x_char   = (const int*)d_in[1];
  const float* word_emb = (const float*)d_in[2];
  const float* char_emb = (const float*)d_in[3];
  const float* conv1_w = (const float*)d_in[4];
  const float* conv1_b = (const float*)d_in[5];
  const float* conv2_w = (const float*)d_in[6];
  const float* conv2_b = (const float*)d_in[7];
  const float* conv3_w = (const float*)d_in[8];
  const float* conv3_b = (const float*)d_in[9];
  const float* w_ih_f = (const float*)d_in[10];
  const float* w_hh_f = (const float*)d_in[11];
  const float* b_f    = (const float*)d_in[12];
  const float* w_ih_b = (const float*)d_in[13];
  const float* w_hh_b = (const float*)d_in[14];
  const float* b_b    = (const float*)d_in[15];
  const float* h0     = (const float*)d_in[16];
  const float* c0     = (const float*)d_in[17];
  const float* fc_w   = (const float*)d_in[18];
  const float* fc_b   = (const float*)d_in[19];
  const float* start_t = (const float*)d_in[20];
  const float* trans  = (const float*)d_in[21];
  const float* end_t  = (const float*)d_in[22];
  int* out = (int*)d_out;

  char* ws = (char*)d_ws;
  auto alloc = [&](size_t bytes) -> char* {
    char* p = ws;
    ws += (bytes + 1023) & ~(size_t)1023;
    return p;
  };
  float* pooled  = (float*)alloc(sizeof(float) * B_ * C_);
  float* biaseff = (float*)alloc(sizeof(float) * 2 * G4_ * B_);
  float* gi      = (float*)alloc(sizeof(float) * 2 * S_ * G4_ * B_);          // 33.5 MB
  float* hbuf    = (float*)alloc(sizeof(float) * 2 * (S_ + 1) * H_ * B_);     // 8.45 MB
  unsigned* hfrag = (unsigned*)alloc(sizeof(unsigned) * 2 * (S_ + 1) * SLAB_); // 8.45 MB
  float* out1    = (float*)alloc(sizeof(float) * B_ * C_ * 48);
  float* out2    = (float*)alloc(sizeof(float) * B_ * C_ * 45);
  float* em      = (float*)alloc(sizeof(float) * B_ * S_ * L_);
  int* hist      = (int*)alloc(sizeof(int) * (S_ - 1) * B_ * L_);

  const int hinit_total = 2 * (S_ + 1) * SLAB_;
  k_hinit<<<(hinit_total + 255) / 256, 256, 0, stream>>>(h0, hfrag);
  k_conv1<<<dim3(32, 2), 256, 0, stream>>>(x_char, char_emb, conv1_w, conv1_b, out1);
  k_conv2<<<dim3(32, 4), 256, 0, stream>>>(out1, conv2_w, conv2_b, out2);
  k_conv3<<<dim3(32, 5), 256, 0, stream>>>(out2, conv3_w, conv3_b, pooled);
  k_biaseff<<<dim3(32, 2), 256, 0, stream>>>(pooled, w_ih_f, b_f, w_ih_b, b_b, biaseff);
  k_gemm_in<<<dim3(8, 32, 2), 256, 0, stream>>>(x, word_emb, w_ih_f, w_ih_b, biaseff, gi);
  k_lstm<<<dim3(NBLKD, 2), 256, 0, stream>>>(w_hh_f, w_hh_b, c0, gi, hbuf, hfrag);
  k_fc<<<(B_ * S_ * L_ + 255) / 256, 256, 0, stream>>>(hbuf, fc_w, fc_b, em);
  k_softmax<<<32, 256, 0, stream>>>(em);
  k_viterbi<<<32, 64, 0, stream>>>(em, x, start_t, trans, end_t, hist, out);
}

// Round 7
// 928.394 us; speedup vs baseline: 1.9510x; 1.1333x over previous
//
#include <hip/hip_runtime.h>
#include <cmath>

#define B_   32
#define S_   128
#define E_   300
#define C_   100
#define EC_  50
#define LC_  50
#define H_   256
#define G4_  1024   // 4*H
#define L_   17
#define DHID_ 400   // E + C
#define NBLKD 8     // lstm blocks per direction
#define SLAB_ 8192  // u32 per (d,t) frag slab: [Nt(2)][Kt(8)][lane(64)][hi m0..3 | lo m4..7]
#define SENT2_ 0x7E007E00u  // fp16-NaN in both halves: legit packed pair never matches
#define KP_   208   // k-pairs per row in packed GEMM operands (416 k, zero-padded from 400)

typedef _Float16 half8 __attribute__((ext_vector_type(8)));
typedef float f32x4 __attribute__((ext_vector_type(4)));
typedef unsigned long long ull;
struct __align__(16) U2 { ull x, y; };

// split fp32 -> (hi fp16, lo fp16 scaled by 2048), packed u32 (hi in low16).
__device__ __forceinline__ unsigned pack_split(float v) {
  _Float16 hi = (fabsf(v) >= 6.104e-5f) ? (_Float16)v : (_Float16)0.0f;
  float hif = (float)hi;
  _Float16 lo = (_Float16)((v - hif) * 2048.0f);
  return (unsigned)__builtin_bit_cast(unsigned short, hi)
       | ((unsigned)__builtin_bit_cast(unsigned short, lo) << 16);
}

// ---------------------------------------------------------------- hfrag init: t=0 from h0, t>=1 sentinel
__global__ void k_hinit(const float* __restrict__ h0, unsigned* __restrict__ hfrag) {
  int idx = blockIdx.x * 256 + threadIdx.x;
  const int total = 2 * (S_ + 1) * SLAB_;
  if (idx >= total) return;
  int sd = idx / SLAB_;           // d*(S+1)+t
  int within = idx % SLAB_;
  int t = sd % (S_ + 1), d = sd / (S_ + 1);
  if (t != 0) { hfrag[idx] = SENT2_; return; }
  int m8 = within & 7;            // 0-3 hi words, 4-7 lo words
  int lane = (within >> 3) & 63;
  int q = within >> 9;            // Nt*8+Kt
  int Kt = q & 7, Nt = q >> 3;
  int m = m8 & 3, isLo = m8 >> 2;
  int k0 = Kt * 32 + (lane >> 4) * 8 + 2 * m;
  int b = Nt * 16 + (lane & 15);
  unsigned p0 = pack_split(h0[((size_t)d * B_ + b) * H_ + k0]);
  unsigned p1 = pack_split(h0[((size_t)d * B_ + b) * H_ + k0 + 1]);
  unsigned hiw = (p0 & 0xFFFFu) | (p1 << 16);
  unsigned low = (p0 >> 16) | (p1 & 0xFFFF0000u);
  hfrag[idx] = isLo ? low : hiw;
}

// ---------------------------------------------------------------- char conv1
__global__ void k_conv1(const int* __restrict__ x_char, const float* __restrict__ char_emb,
                        const float* __restrict__ w1, const float* __restrict__ b1,
                        float* __restrict__ out1) {
  int b = blockIdx.x;
  int ot = blockIdx.y;
  __shared__ float ce[EC_ * 52];
  __shared__ float wl[50 * 150];
  __shared__ int ids[LC_];
  int tid = threadIdx.x;
  if (tid < LC_) ids[tid] = x_char[b * LC_ + tid];
  __syncthreads();
  for (int idx = tid; idx < LC_ * EC_; idx += 256) {
    int t = idx / EC_, ec = idx % EC_;
    ce[ec * 52 + t] = char_emb[ids[t] * EC_ + ec];
  }
  int obase = ot * 50;
  for (int idx = tid; idx < 50 * 150; idx += 256)
    wl[idx] = w1[obase * 150 + idx];
  __syncthreads();
  for (int idx = tid; idx < 50 * 48; idx += 256) {
    int o = idx / 48, t = idx % 48;
    float acc = b1[obase + o];
    const float* wr = &wl[o * 150];
    for (int c = 0; c < EC_; ++c) {
      const float* ip = &ce[c * 52 + t];
      acc += wr[c * 3 + 0] * ip[0] + wr[c * 3 + 1] * ip[1] + wr[c * 3 + 2] * ip[2];
    }
    out1[((size_t)b * C_ + obase + o) * 48 + t] = fmaxf(acc, 0.0f);
  }
}

// ---------------------------------------------------------------- char conv2
__global__ void k_conv2(const float* __restrict__ in, const float* __restrict__ w2,
                        const float* __restrict__ b2, float* __restrict__ out2) {
  int b = blockIdx.x, ot = blockIdx.y;
  __shared__ float il[C_ * 48];
  __shared__ float wl[25 * 400];
  int tid = threadIdx.x;
  for (int idx = tid; idx < C_ * 48; idx += 256) il[idx] = in[(size_t)b * C_ * 48 + idx];
  int obase = ot * 25;
  for (int idx = tid; idx < 25 * 400; idx += 256) wl[idx] = w2[obase * 400 + idx];
  __syncthreads();
  for (int idx = tid; idx < 25 * 45; idx += 256) {
    int o = idx / 45, t = idx % 45;
    float acc = b2[obase + o];
    const float* wr = &wl[o * 400];
    for (int c = 0; c < C_; ++c) {
      const float* ip = &il[c * 48 + t];
      acc += wr[c * 4 + 0] * ip[0] + wr[c * 4 + 1] * ip[1] +
             wr[c * 4 + 2] * ip[2] + wr[c * 4 + 3] * ip[3];
    }
    out2[((size_t)b * C_ + obase + o) * 45 + t] = fmaxf(acc, 0.0f);
  }
}

// ---------------------------------------------------------------- char conv3 + maxpool
__global__ void k_conv3(const float* __restrict__ in, const float* __restrict__ w3,
                        const float* __restrict__ b3, float* __restrict__ pooled) {
  int b = blockIdx.x, ot = blockIdx.y;
  __shared__ float il[C_ * 45];
  __shared__ float wl[20 * 500];
  __shared__ float o3[20 * 44];
  int tid = threadIdx.x;
  for (int idx = tid; idx < C_ * 45; idx += 256) il[idx] = in[(size_t)b * C_ * 45 + idx];
  int obase = ot * 20;
  for (int idx = tid; idx < 20 * 500; idx += 256) wl[idx] = w3[obase * 500 + idx];
  __syncthreads();
  for (int idx = tid; idx < 20 * 41; idx += 256) {
    int o = idx / 41, t = idx % 41;
    float acc = b3[obase + o];
    const float* wr = &wl[o * 500];
    for (int c = 0; c < C_; ++c) {
      const float* ip = &il[c * 45 + t];
      acc += wr[c * 5 + 0] * ip[0] + wr[c * 5 + 1] * ip[1] + wr[c * 5 + 2] * ip[2] +
             wr[c * 5 + 3] * ip[3] + wr[c * 5 + 4] * ip[4];
    }
    o3[o * 44 + t] = fmaxf(acc, 0.0f);
  }
  __syncthreads();
  if (tid < 20) {
    float m = o3[tid * 44];
    for (int t = 1; t < 41; ++t) m = fmaxf(m, o3[tid * 44 + t]);
    pooled[b * C_ + obase + tid] = m;
  }
}

// ---------------------------------------------------------------- prep: w_ih -> hi/lo pair format [d][j][k2]
__global__ void k_prep_w(const float* __restrict__ wf, const float* __restrict__ wb,
                         unsigned* __restrict__ apH, unsigned* __restrict__ apL) {
  int idx = blockIdx.x * 256 + threadIdx.x;
  if (idx >= 2 * G4_ * KP_) return;
  int d = idx / (G4_ * KP_);
  int rem = idx % (G4_ * KP_);
  int j = rem / KP_, k2 = rem % KP_;
  const float* w = d ? wb : wf;
  float v0 = 0.f, v1 = 0.f;
  if (k2 < 200) { v0 = w[(size_t)j * DHID_ + 2 * k2]; v1 = w[(size_t)j * DHID_ + 2 * k2 + 1]; }
  unsigned p0 = pack_split(v0), p1 = pack_split(v1);
  apH[idx] = (p0 & 0xFFFFu) | (p1 << 16);
  apL[idx] = (p0 >> 16) | (p1 & 0xFFFF0000u);
}

// ---------------------------------------------------------------- prep: gathered [emb | pooled] rows -> pairs [r][k2]
__global__ void k_prep_b(const int* __restrict__ x, const float* __restrict__ word_emb,
                         const float* __restrict__ pooled,
                         unsigned* __restrict__ bpH, unsigned* __restrict__ bpL) {
  int r = blockIdx.x;       // 0..4095 = t*32+b
  int k2 = threadIdx.x;
  if (k2 >= KP_) return;
  int t = r >> 5, b = r & 31;
  float v0 = 0.f, v1 = 0.f;
  if (k2 < 150) {
    const float* e = word_emb + (size_t)x[b * S_ + t] * E_;
    v0 = e[2 * k2]; v1 = e[2 * k2 + 1];
  } else if (k2 < 200) {
    v0 = pooled[b * C_ + 2 * k2 - 300];
    v1 = pooled[b * C_ + 2 * k2 - 299];
  }
  unsigned p0 = pack_split(v0), p1 = pack_split(v1);
  bpH[(size_t)r * KP_ + k2] = (p0 & 0xFFFFu) | (p1 << 16);
  bpL[(size_t)r * KP_ + k2] = (p0 >> 16) | (p1 & 0xFFFF0000u);
}

// ---------------------------------------------------------------- input GEMM via MFMA fp16x2 -> gi[d][t][j][b]
// Block: 128 j x 128 r, K=416 (13 Kt). A = w_ih pairs, B = [emb|pooled] pairs; bias added in epilogue
// (k_biaseff eliminated: pooled part lives in B). Frag-slab LDS staging identical in structure to k_lstm.
__global__ __launch_bounds__(256) void k_gemm(
    const unsigned* __restrict__ apH, const unsigned* __restrict__ apL,
    const unsigned* __restrict__ bpH, const unsigned* __restrict__ bpL,
    const float* __restrict__ b_f, const float* __restrict__ b_b,
    float* __restrict__ gi) {
  const int jt = blockIdx.x, rt = blockIdx.y, d = blockIdx.z;
  const int j0 = jt * 128, r0 = rt * 128;
  const int tid = threadIdx.x;
  const int w = tid >> 6, l = tid & 63;
  const int lx = l & 15, lq = l >> 4;

  __shared__ unsigned aH[2048], aL[2048], bH[2048], bL[2048];  // 32 KB total

  f32x4 acch[2][8], accl[2][8];
#pragma unroll
  for (int mt = 0; mt < 2; ++mt)
#pragma unroll
    for (int nt = 0; nt < 8; ++nt) {
      f32x4 z = {0.f, 0.f, 0.f, 0.f};
      acch[mt][nt] = z; accl[mt][nt] = z;
    }

  const int jr = tid >> 1, hh = tid & 1;
  const int q_st = jr >> 4, lane_lo = jr & 15;
  const unsigned* arH = apH + ((size_t)(d * G4_ + j0 + jr)) * KP_ + hh * 8;
  const unsigned* arL = apL + ((size_t)(d * G4_ + j0 + jr)) * KP_ + hh * 8;
  const unsigned* brH = bpH + ((size_t)(r0 + jr)) * KP_ + hh * 8;
  const unsigned* brL = bpL + ((size_t)(r0 + jr)) * KP_ + hh * 8;
  const int w0 = (q_st * 64 + lane_lo + 32 * hh) * 4;        // lq = 2hh slot
  const int w1 = (q_st * 64 + lane_lo + 32 * hh + 16) * 4;   // lq = 2hh+1 slot

  for (int Kt = 0; Kt < 13; ++Kt) {
    uint4 a0 = *(const uint4*)(arH + Kt * 16);
    uint4 a1 = *(const uint4*)(arH + Kt * 16 + 4);
    uint4 c0 = *(const uint4*)(arL + Kt * 16);
    uint4 c1 = *(const uint4*)(arL + Kt * 16 + 4);
    uint4 e0 = *(const uint4*)(brH + Kt * 16);
    uint4 e1 = *(const uint4*)(brH + Kt * 16 + 4);
    uint4 f0 = *(const uint4*)(brL + Kt * 16);
    uint4 f1 = *(const uint4*)(brL + Kt * 16 + 4);
    *(uint4*)&aH[w0] = a0; *(uint4*)&aH[w1] = a1;
    *(uint4*)&aL[w0] = c0; *(uint4*)&aL[w1] = c1;
    *(uint4*)&bH[w0] = e0; *(uint4*)&bH[w1] = e1;
    *(uint4*)&bL[w0] = f0; *(uint4*)&bL[w1] = f1;
    __syncthreads();

    union u4h { uint4 u; half8 h; };
    u4h AH0, AH1, AL0, AL1;
    AH0.u = *(const uint4*)&aH[((2 * w + 0) * 64 + l) * 4];
    AH1.u = *(const uint4*)&aH[((2 * w + 1) * 64 + l) * 4];
    AL0.u = *(const uint4*)&aL[((2 * w + 0) * 64 + l) * 4];
    AL1.u = *(const uint4*)&aL[((2 * w + 1) * 64 + l) * 4];
#pragma unroll
    for (int nt = 0; nt < 8; ++nt) {
      u4h BHn, BLn;
      BHn.u = *(const uint4*)&bH[(nt * 64 + l) * 4];
      BLn.u = *(const uint4*)&bL[(nt * 64 + l) * 4];
      acch[0][nt] = __builtin_amdgcn_mfma_f32_16x16x32_f16(AH0.h, BHn.h, acch[0][nt], 0, 0, 0);
      accl[0][nt] = __builtin_amdgcn_mfma_f32_16x16x32_f16(AH0.h, BLn.h, accl[0][nt], 0, 0, 0);
      accl[0][nt] = __builtin_amdgcn_mfma_f32_16x16x32_f16(AL0.h, BHn.h, accl[0][nt], 0, 0, 0);
      acch[1][nt] = __builtin_amdgcn_mfma_f32_16x16x32_f16(AH1.h, BHn.h, acch[1][nt], 0, 0, 0);
      accl[1][nt] = __builtin_amdgcn_mfma_f32_16x16x32_f16(AH1.h, BLn.h, accl[1][nt], 0, 0, 0);
      accl[1][nt] = __builtin_amdgcn_mfma_f32_16x16x32_f16(AL1.h, BHn.h, accl[1][nt], 0, 0, 0);
    }
    __syncthreads();
  }

  const float* bias = d ? b_b : b_f;
  const float inv2048 = 1.0f / 2048.0f;
#pragma unroll
  for (int mt = 0; mt < 2; ++mt) {
#pragma unroll
    for (int nt = 0; nt < 8; ++nt) {
      int rr = r0 + nt * 16 + lx;
      int tt = rr >> 5, bb = rr & 31;
      float* dst = gi + ((size_t)(d * S_ + tt) * G4_) * B_ + bb;
#pragma unroll
      for (int r4 = 0; r4 < 4; ++r4) {
        int j = j0 + (2 * w + mt) * 16 + lq * 4 + r4;
        dst[(size_t)j * B_] = acch[mt][nt][r4] + accl[mt][nt][r4] * inv2048 + bias[j];
      }
    }
  }
}

// ---------------------------------------------------------------- BiLSTM recurrence via MFMA fp16x2 (R6, unchanged)
__global__ __launch_bounds__(256, 1) void k_lstm(
    const float* __restrict__ w_hh_f, const float* __restrict__ w_hh_b,
    const float* __restrict__ c0, const float* __restrict__ gi,
    float* __restrict__ hbuf, unsigned* __restrict__ hfrag) {
  const int iblk = blockIdx.x;     // 0..7
  const int d = blockIdx.y;
  const float* whh = d ? w_hh_b : w_hh_f;
  const int tid = threadIdx.x;
  const int w = tid >> 6;          // wave index = gate (i,f,g,o)
  const int l = tid & 63;
  const int lx = l & 15, lq = l >> 4;
  const int u0 = iblk * 32;

  __shared__ ull slh[2048];
  __shared__ ull sll[2048];
  __shared__ float gl[4 * 32 * 33];
  __shared__ unsigned ps[2 * 576];

  half8 whi[2][8], wlo[2][8];
#pragma unroll
  for (int Mt = 0; Mt < 2; ++Mt) {
#pragma unroll
    for (int Kt = 0; Kt < 8; ++Kt) {
      int row = w * H_ + u0 + Mt * 16 + lx;
      int kk0 = Kt * 32 + lq * 8;
      const float* src = whh + (size_t)row * H_ + kk0;
      float4 f0 = *(const float4*)src;
      float4 f1 = *(const float4*)(src + 4);
      float wv[8] = {f0.x, f0.y, f0.z, f0.w, f1.x, f1.y, f1.z, f1.w};
      union { unsigned short s[8]; half8 h; } HI, LO;
#pragma unroll
      for (int j = 0; j < 8; ++j) {
        float v = wv[j];
        _Float16 hi = (fabsf(v) >= 6.104e-5f) ? (_Float16)v : (_Float16)0.0f;
        float hif = (float)hi;
        _Float16 lo = (_Float16)((v - hif) * 2048.0f);
        HI.s[j] = __builtin_bit_cast(unsigned short, hi);
        LO.s[j] = __builtin_bit_cast(unsigned short, lo);
      }
      whi[Mt][Kt] = HI.h;
      wlo[Mt][Kt] = LO.h;
    }
  }

  const int bc = tid & 31, cw = tid >> 5;
  float creg[4];
#pragma unroll
  for (int cu = 0; cu < 4; ++cu)
    creg[cu] = c0[((size_t)d * B_ + bc) * H_ + u0 + cu * 8 + cw];

  const int pNt = bc >> 4;
  const int pm = cw >> 1;
  const bool phi = (cw & 1) == 0;
  const int plane = bc & 15;
  const float inv2048 = 1.0f / 2048.0f;

  for (int t = 0; t < S_; ++t) {
    int torig = d ? (S_ - 1 - t) : t;

    f32x4 acch[2][2], accl[2][2];
    {
      const float* gbase = gi + ((size_t)(d * S_ + torig) * G4_) * B_;
#pragma unroll
      for (int Mt = 0; Mt < 2; ++Mt)
#pragma unroll
        for (int Nt = 0; Nt < 2; ++Nt) {
          f32x4 v;
#pragma unroll
          for (int r = 0; r < 4; ++r) {
            int j = w * H_ + u0 + Mt * 16 + lq * 4 + r;
            v[r] = gbase[(size_t)j * B_ + Nt * 16 + lx];
          }
          acch[Mt][Nt] = v;
          f32x4 z = {0.f, 0.f, 0.f, 0.f};
          accl[Mt][Nt] = z;
        }
    }

    const ull* hp = (const ull*)(hfrag + (size_t)(d * (S_ + 1) + t) * SLAB_);
    ull pv[4][4];
#pragma unroll
    for (int c = 0; c < 4; ++c) {
      size_t base = ((size_t)(w * 4 + c) * 64 + l) * 4;
#pragma unroll
      for (int j = 0; j < 4; ++j)
        pv[c][j] = __hip_atomic_load(&hp[base + j], __ATOMIC_RELAXED,
                                     __HIP_MEMORY_SCOPE_AGENT);
    }
    for (;;) {
      bool pending = false;
#pragma unroll
      for (int c = 0; c < 4; ++c)
#pragma unroll
        for (int j = 0; j < 4; ++j)
          pending |= ((unsigned)pv[c][j] == SENT2_) |
                     ((unsigned)(pv[c][j] >> 32) == SENT2_);
      if (!pending) break;
#pragma unroll
      for (int c = 0; c < 4; ++c) {
        size_t base = ((size_t)(w * 4 + c) * 64 + l) * 4;
#pragma unroll
        for (int j = 0; j < 4; ++j)
          pv[c][j] = __hip_atomic_load(&hp[base + j], __ATOMIC_RELAXED,
                                       __HIP_MEMORY_SCOPE_AGENT);
      }
    }
#pragma unroll
    for (int c = 0; c < 4; ++c) {
      int idx = ((w * 4 + c) * 64 + l) * 2;
      U2 vh; vh.x = pv[c][0]; vh.y = pv[c][1];
      U2 vl; vl.x = pv[c][2]; vl.y = pv[c][3];
      *(U2*)&slh[idx] = vh;
      *(U2*)&sll[idx] = vl;
    }
    __syncthreads();

#pragma unroll
    for (int Kt = 0; Kt < 8; ++Kt) {
      half8 Bhi[2], Blo[2];
#pragma unroll
      for (int Nt = 0; Nt < 2; ++Nt) {
        int idx = ((Nt * 8 + Kt) * 64 + l) * 2;
        union { U2 u; half8 h; } UH, UL;
        UH.u = *(const U2*)&slh[idx];
        UL.u = *(const U2*)&sll[idx];
        Bhi[Nt] = UH.h;
        Blo[Nt] = UL.h;
      }
#pragma unroll
      for (int Mt = 0; Mt < 2; ++Mt)
#pragma unroll
        for (int Nt = 0; Nt < 2; ++Nt) {
          acch[Mt][Nt] = __builtin_amdgcn_mfma_f32_16x16x32_f16(
              whi[Mt][Kt], Bhi[Nt], acch[Mt][Nt], 0, 0, 0);
          accl[Mt][Nt] = __builtin_amdgcn_mfma_f32_16x16x32_f16(
              whi[Mt][Kt], Blo[Nt], accl[Mt][Nt], 0, 0, 0);
          accl[Mt][Nt] = __builtin_amdgcn_mfma_f32_16x16x32_f16(
              wlo[Mt][Kt], Bhi[Nt], accl[Mt][Nt], 0, 0, 0);
        }
    }

#pragma unroll
    for (int Mt = 0; Mt < 2; ++Mt)
#pragma unroll
      for (int Nt = 0; Nt < 2; ++Nt)
#pragma unroll
        for (int r = 0; r < 4; ++r) {
          int ul = Mt * 16 + lq * 4 + r;
          gl[(w * 32 + ul) * 33 + Nt * 16 + lx] =
              acch[Mt][Nt][r] + accl[Mt][Nt][r] * inv2048;
        }
    __syncthreads();

    float hreg[4];
#pragma unroll
    for (int cu = 0; cu < 4; ++cu) {
      int u = cu * 8 + cw;
      float g_i = gl[(0 * 32 + u) * 33 + bc];
      float g_f = gl[(1 * 32 + u) * 33 + bc];
      float g_g = gl[(2 * 32 + u) * 33 + bc];
      float g_o = gl[(3 * 32 + u) * 33 + bc];
      float si = 1.f / (1.f + __expf(-g_i));
      float sf = 1.f / (1.f + __expf(-g_f));
      float so = 1.f / (1.f + __expf(-g_o));
      float tg = 1.f - 2.f / (__expf(2.f * g_g) + 1.f);
      float cn = sf * creg[cu] + si * tg;
      float tc = 1.f - 2.f / (__expf(2.f * cn) + 1.f);
      float hn = so * tc;
      creg[cu] = cn;
      hreg[cu] = hn;
      unsigned me = pack_split(hn);
      unsigned pa = (unsigned)__shfl_xor((int)me, 32, 64);
      unsigned je = (cw & 1) ? pa : me;
      unsigned jo = (cw & 1) ? me : pa;
      unsigned hiw = (je & 0xFFFFu) | (jo << 16);
      unsigned low = (je >> 16) | (jo & 0xFFFF0000u);
      int lane2 = (cu << 4) | plane;
      int m8 = phi ? pm : (4 + pm);
      ps[pNt * 576 + lane2 * 9 + m8] = phi ? hiw : low;
    }
    __syncthreads();

    {
      ull* slab64 = (ull*)(hfrag + (size_t)(d * (S_ + 1) + t + 1) * SLAB_);
#pragma unroll
      for (int hh2 = 0; hh2 < 2; ++hh2) {
        int r = tid;
        int Nt = hh2;
        int lane2 = r >> 2, m2 = r & 3;
        unsigned a = ps[Nt * 576 + lane2 * 9 + 2 * m2];
        unsigned b = ps[Nt * 576 + lane2 * 9 + 2 * m2 + 1];
        ull v = (ull)a | ((ull)b << 32);
        __hip_atomic_store(&slab64[(size_t)(Nt * 8 + iblk) * 256 + r], v,
                           __ATOMIC_RELAXED, __HIP_MEMORY_SCOPE_AGENT);
      }
      float* hb = hbuf + (size_t)(d * (S_ + 1) + t + 1) * (H_ * B_) + u0 * B_;
#pragma unroll
      for (int cu = 0; cu < 4; ++cu) hb[cu * 256 + tid] = hreg[cu];
    }
  }
}

// ---------------------------------------------------------------- FC -> emissions em[b][s][l], coalesced
// block per s; lanes = b so hbuf[k][b] reads are 128B lines; fc_w transposed in LDS; k-split x8 + LDS reduce.
__global__ __launch_bounds__(256) void k_fc(const float* __restrict__ hbuf,
                                            const float* __restrict__ fc_w,
                                            const float* __restrict__ fc_b,
                                            float* __restrict__ em) {
  const int s = blockIdx.x;
  const int tid = threadIdx.x;
  __shared__ float wT[512 * 18];    // [k][l] pad 18
  __shared__ float psum[256 * 18];
  for (int i = tid; i < L_ * 512; i += 256) {
    int l = i / 512, k = i % 512;
    wT[k * 18 + l] = fc_w[i];
  }
  __syncthreads();
  const int b = tid & 31, kq = tid >> 5;
  const float* hf = hbuf + (size_t)(s + 1) * (H_ * B_);
  const float* hbk = hbuf + (size_t)(S_ + 1 + (S_ - s)) * (H_ * B_);
  float acc[L_];
#pragma unroll
  for (int l = 0; l < L_; ++l) acc[l] = 0.f;
  for (int i = 0; i < 64; ++i) {
    int k = kq * 64 + i;   // 0..511
    float hv = (k < 256) ? hf[k * 32 + b] : hbk[(k - 256) * 32 + b];
    const float* wr = &wT[k * 18];
#pragma unroll
    for (int l = 0; l < L_; ++l) acc[l] = fmaf(hv, wr[l], acc[l]);
  }
#pragma unroll
  for (int l = 0; l < L_; ++l) psum[tid * 18 + l] = acc[l];
  __syncthreads();
  for (int idx = tid; idx < B_ * L_; idx += 256) {
    int bb = idx & 31, l = idx >> 5;
    float sum = fc_b[l];
    for (int q = 0; q < 8; ++q) sum += psum[(q * 32 + bb) * 18 + l];
    em[((size_t)bb * S_ + s) * L_ + l] = sum;
  }
}

// ---------------------------------------------------------------- fused softmax(seq) + viterbi, all-LDS
__global__ void k_smv(const float* __restrict__ em, const int* __restrict__ x,
                      const float* __restrict__ start_t, const float* __restrict__ trans,
                      const float* __restrict__ end_t, int* __restrict__ out) {
  int b = blockIdx.x;
  int tid = threadIdx.x;  // 64
  __shared__ float e[S_ * L_];
  __shared__ float tr[L_ * L_];
  __shared__ float sc[2][L_];
  __shared__ int hist[(S_ - 1) * L_];
  __shared__ int tags[S_];
  for (int i = tid; i < S_ * L_; i += 64) e[i] = em[(size_t)b * S_ * L_ + i];
  for (int i = tid; i < L_ * L_; i += 64) tr[i] = trans[i];
  __syncthreads();
  if (tid < L_) {
    int l = tid;
    float m = -INFINITY;
    for (int s = 0; s < S_; ++s) m = fmaxf(m, e[s * L_ + l]);
    float sum = 0.f;
    for (int s = 0; s < S_; ++s) {
      float ex = expf(e[s * L_ + l] - m);
      e[s * L_ + l] = ex;
      sum += ex;
    }
    for (int s = 0; s < S_; ++s) e[s * L_ + l] = e[s * L_ + l] / sum;
  }
  __syncthreads();
  if (tid < L_) sc[0][tid] = start_t[tid] + e[tid];
  __syncthreads();
  int cbuf = 0;
  for (int t = 1; t < S_; ++t) {
    if (tid < L_) {
      int j = tid;
      float ev = e[t * L_ + j];
      float best = -INFINITY;
      int arg = 0;
      for (int i = 0; i < L_; ++i) {
        float v = (sc[cbuf][i] + tr[i * L_ + j]) + ev;
        if (v > best) { best = v; arg = i; }  // strict >: first occurrence like np.argmax
      }
      int maskt = (x[b * S_ + t] != 0);
      sc[cbuf ^ 1][j] = maskt ? best : sc[cbuf][j];
      hist[(t - 1) * L_ + j] = arg;
    }
    __syncthreads();
    cbuf ^= 1;
  }
  if (tid == 0) {
    float best = -INFINITY;
    int last = 0;
    for (int j = 0; j < L_; ++j) {
      float v = sc[cbuf][j] + end_t[j];
      if (v > best) { best = v; last = j; }
    }
    int cur = last;
    tags[S_ - 1] = cur;
    for (int p = S_ - 2; p >= 0; --p) {
      if (x[b * S_ + p + 1] != 0) cur = hist[p * L_ + cur];
      tags[p] = cur;
    }
  }
  __syncthreads();
  for (int s = tid; s < S_; s += 64) out[b * S_ + s] = tags[s];
}

// ---------------------------------------------------------------- launch
extern "C" void kernel_launch(void* const* d_in, const int* in_sizes, int n_in,
                              void* d_out, int out_size, void* d_ws, size_t ws_size,
                              hipStream_t stream) {
  const int* x        = (const int*)d_in[0];
  const int* x_char   = (const int*)d_in[1];
  const float* word_emb = (const float*)d_in[2];
  const float* char_emb = (const float*)d_in[3];
  const float* conv1_w = (const float*)d_in[4];
  const float* conv1_b = (const float*)d_in[5];
  const float* conv2_w = (const float*)d_in[6];
  const float* conv2_b = (const float*)d_in[7];
  const float* conv3_w = (const float*)d_in[8];
  const float* conv3_b = (const float*)d_in[9];
  const float* w_ih_f = (const float*)d_in[10];
  const float* w_hh_f = (const float*)d_in[11];
  const float* b_f    = (const float*)d_in[12];
  const float* w_ih_b = (const float*)d_in[13];
  const float* w_hh_b = (const float*)d_in[14];
  const float* b_b    = (const float*)d_in[15];
  const float* h0     = (const float*)d_in[16];
  const float* c0     = (const float*)d_in[17];
  const float* fc_w   = (const float*)d_in[18];
  const float* fc_b   = (const float*)d_in[19];
  const float* start_t = (const float*)d_in[20];
  const float* trans  = (const float*)d_in[21];
  const float* end_t  = (const float*)d_in[22];
  int* out = (int*)d_out;

  char* ws = (char*)d_ws;
  auto alloc = [&](size_t bytes) -> char* {
    char* p = ws;
    ws += (bytes + 1023) & ~(size_t)1023;
    return p;
  };
  float* pooled  = (float*)alloc(sizeof(float) * B_ * C_);
  float* gi      = (float*)alloc(sizeof(float) * 2 * S_ * G4_ * B_);            // 33.5 MB
  float* hbuf    = (float*)alloc(sizeof(float) * 2 * (S_ + 1) * H_ * B_);       // 8.45 MB
  unsigned* hfrag = (unsigned*)alloc(sizeof(unsigned) * 2 * (S_ + 1) * SLAB_);  // 8.45 MB
  unsigned* apH  = (unsigned*)alloc(sizeof(unsigned) * 2 * G4_ * KP_);          // 1.7 MB
  unsigned* apL  = (unsigned*)alloc(sizeof(unsigned) * 2 * G4_ * KP_);
  unsigned* bpH  = (unsigned*)alloc(sizeof(unsigned) * 4096 * KP_);             // 3.4 MB
  unsigned* bpL  = (unsigned*)alloc(sizeof(unsigned) * 4096 * KP_);
  float* out1    = (float*)alloc(sizeof(float) * B_ * C_ * 48);
  float* out2    = (float*)alloc(sizeof(float) * B_ * C_ * 45);
  float* em      = (float*)alloc(sizeof(float) * B_ * S_ * L_);

  const int hinit_total = 2 * (S_ + 1) * SLAB_;
  k_hinit<<<(hinit_total + 255) / 256, 256, 0, stream>>>(h0, hfrag);
  k_prep_w<<<(2 * G4_ * KP_ + 255) / 256, 256, 0, stream>>>(w_ih_f, w_ih_b, apH, apL);
  k_conv1<<<dim3(32, 2), 256, 0, stream>>>(x_char, char_emb, conv1_w, conv1_b, out1);
  k_conv2<<<dim3(32, 4), 256, 0, stream>>>(out1, conv2_w, conv2_b, out2);
  k_conv3<<<dim3(32, 5), 256, 0, stream>>>(out2, conv3_w, conv3_b, pooled);
  k_prep_b<<<4096, 256, 0, stream>>>(x, word_emb, pooled, bpH, bpL);
  k_gemm<<<dim3(8, 32, 2), 256, 0, stream>>>(apH, apL, bpH, bpL, b_f, b_b, gi);
  k_lstm<<<dim3(NBLKD, 2), 256, 0, stream>>>(w_hh_f, w_hh_b, c0, gi, hbuf, hfrag);
  k_fc<<<S_, 256, 0, stream>>>(hbuf, fc_w, fc_b, em);
  k_smv<<<B_, 64, 0, stream>>>(em, x, start_t, trans, end_t, out);
}